// Round 3
// baseline (526.883 us; speedup 1.0000x reference)
//
#include <hip/hip_runtime.h>

#define N_NODES 100000
#define N_EDGES 1600000
#define NEG_SLOPE 0.2f
#define BN_EPS 1e-5f

typedef __attribute__((ext_vector_type(8))) short short8;
typedef __attribute__((ext_vector_type(4))) float floatx4;
typedef __attribute__((ext_vector_type(8))) unsigned short u16x8;

// ---------------- workspace layout (bytes) ----------------
static const size_t OFF_AB   = 0;            // feats bf16 fragment-ordered [N_PAD,128]
static const size_t OFF_BB   = 25624576;     // weights bf16 fragment-ordered [512,128]
static const size_t OFF_H    = 25755648;     // h bf16 [N+1,256] (row N = sentinel zeros)
static const size_t OFF_RES  = 76956672;     // res+bias bf16 [N,256]
static const size_t OFF_EL   = 128156672;    // el [N+1,4] f32 (row N = -1e30 sentinel)
static const size_t OFF_ER   = 129757184;    // er [N,4] f32
static const size_t OFF_DEG  = 131357184;    // deg [N] i32
static const size_t OFF_RS   = 131757184;    // padded row_start [N+1] i32
static const size_t OFF_CUR  = 132157568;    // cursor [N] i32
static const size_t OFF_ESRC = 132557568;    // padded edge src ids [<=2.0M] i32
static const size_t OFF_BS   = 142157568;    // block sums [128] i32
static const size_t OFF_BN   = 142158080;    // bn accum [128] f32
// total ~142.2 MB

__device__ __forceinline__ unsigned short f2bf(float x) {
  unsigned int u = __float_as_uint(x);
  unsigned int r = (u + 0x7fffu + ((u >> 16) & 1u)) >> 16;   // RNE
  return (unsigned short)r;
}
__device__ __forceinline__ float bf2f(unsigned short u) {
  return __uint_as_float(((unsigned int)u) << 16);
}

// ---------------- fused pre-pass: cvt_a | edge count | cvt_w | sentinels ----
__global__ __launch_bounds__(256) void k_pre(
    const float* __restrict__ feats, const float* __restrict__ fc_w,
    const float* __restrict__ res_w, const int* __restrict__ dst,
    unsigned short* __restrict__ Ab, unsigned short* __restrict__ Bb,
    int* __restrict__ deg, unsigned short* __restrict__ hbuf,
    float* __restrict__ el)
{
  const int b = blockIdx.x;
  if (b < 6256) {                                // ---- cvt_a: N_PAD*16 chunks
    int c = b * 256 + threadIdx.x;
    int r = c >> 4, j = c & 15;
    unsigned short v[8];
    if (r < N_NODES) {
      const float* p = feats + (size_t)r * 128 + j * 8;
      float4 a = *(const float4*)p, bb = *(const float4*)(p + 4);
      v[0]=f2bf(a.x); v[1]=f2bf(a.y); v[2]=f2bf(a.z); v[3]=f2bf(a.w);
      v[4]=f2bf(bb.x); v[5]=f2bf(bb.y); v[6]=f2bf(bb.z); v[7]=f2bf(bb.w);
    } else {
      for (int i = 0; i < 8; i++) v[i] = 0;
    }
    size_t idx = (size_t)(r >> 7) * 2048 + ((r >> 4) & 7) * 256 + (j >> 2) * 64
               + (r & 15) + 16 * (j & 3);
    *(short8*)(Ab + idx * 8) = *(short8*)v;
  } else if (b < 12506) {                        // ---- count degrees
    int e = (b - 6256) * 256 + threadIdx.x;
    if (e < N_EDGES) atomicAdd(&deg[dst[e]], 1);
  } else if (b < 12538) {                        // ---- cvt_w: 8192 chunks
    int c = (b - 12506) * 256 + threadIdx.x;
    int n = c >> 4, j = c & 15;
    const float* W = (n < 256) ? (fc_w + (size_t)n * 128) : (res_w + (size_t)(n - 256) * 128);
    const float* p = W + j * 8;
    float4 a = *(const float4*)p, bb = *(const float4*)(p + 4);
    unsigned short v[8];
    v[0]=f2bf(a.x); v[1]=f2bf(a.y); v[2]=f2bf(a.z); v[3]=f2bf(a.w);
    v[4]=f2bf(bb.x); v[5]=f2bf(bb.y); v[6]=f2bf(bb.z); v[7]=f2bf(bb.w);
    size_t idx = (size_t)(n >> 7) * 2048 + ((n >> 4) & 7) * 256 + (j >> 2) * 64
               + (n & 15) + 16 * (j & 3);
    *(short8*)(Bb + idx * 8) = *(short8*)v;
  } else {                                       // ---- sentinel row init
    const int t = threadIdx.x;
    hbuf[(size_t)N_NODES * 256 + t] = 0;         // zero h row for dummy src
    if (t < 4) el[N_NODES * 4 + t] = -1e30f;     // weight-0 logit for dummy src
  }
}

// ---------------- MFMA projection + fused el/er -----------------------------
// grid (782, 2): block stages A once, inner loop computes h-half (nb=y) and
// res-half (nb=y+2) -> A fetched 2x instead of 4x.
__global__ __launch_bounds__(256) void k_mm(
    const unsigned short* __restrict__ Ab, const unsigned short* __restrict__ Bb,
    const float* __restrict__ bias, const float* __restrict__ attn_l,
    const float* __restrict__ attn_r,
    unsigned short* __restrict__ hbuf, unsigned short* __restrict__ resbuf,
    float* __restrict__ el, float* __restrict__ er)
{
  __shared__ unsigned short sA[16384];  // 32 KB, fragment-ordered A block
  const int tid = threadIdx.x;
  const int w = tid >> 6, L = tid & 63;
  const int blk = blockIdx.x;

  {  // stage A: contiguous 32 KB, global_load_lds width 16
    const unsigned short* ga = Ab + (size_t)blk * 16384;
    #pragma unroll
    for (int i = 0; i < 8; i++) {
      int off = (i * 256 + w * 64) * 8;
      __builtin_amdgcn_global_load_lds(
          (const __attribute__((address_space(1))) unsigned int*)(ga + off + L * 8),
          (__attribute__((address_space(3))) unsigned int*)(sA + off),
          16, 0, 0);
    }
  }
  const int mh = w & 1, nh = w >> 1;
  __syncthreads();

  for (int wb = 0; wb < 2; ++wb) {
    const int nb = blockIdx.y + wb * 2;
    floatx4 acc[4][4] = {};
    const unsigned short* gb = Bb + ((size_t)nb * 2048 + nh * 4 * 256) * 8 + L * 8;
    #pragma unroll
    for (int s = 0; s < 4; s++) {
      short8 a[4], b[4];
      #pragma unroll
      for (int t = 0; t < 4; t++)
        a[t] = *(const short8*)(sA + ((mh * 4 + t) * 256 + s * 64 + L) * 8);
      #pragma unroll
      for (int t = 0; t < 4; t++)
        b[t] = *(const short8*)(gb + ((size_t)t * 256 + s * 64) * 8);
      #pragma unroll
      for (int mt = 0; mt < 4; mt++)
        #pragma unroll
        for (int nt = 0; nt < 4; nt++)
          acc[mt][nt] = __builtin_amdgcn_mfma_f32_16x16x32_bf16(a[mt], b[nt], acc[mt][nt], 0, 0, 0);
    }

    const int q = L >> 4, cn = L & 15;
    const int r0 = blk * 128 + mh * 64;
    if (nb < 2) {
      const int head = nb * 2 + nh;            // this wave owns one full head
      const int col0 = nb * 128 + nh * 64;
      float al[4], ar[4];
      #pragma unroll
      for (int nt = 0; nt < 4; nt++) {
        al[nt] = attn_l[head * 64 + nt * 16 + cn];
        ar[nt] = attn_r[head * 64 + nt * 16 + cn];
      }
      #pragma unroll
      for (int mt = 0; mt < 4; mt++)
        #pragma unroll
        for (int r = 0; r < 4; r++) {
          const int row = r0 + mt * 16 + q * 4 + r;
          float pl = 0.f, pr = 0.f;
          #pragma unroll
          for (int nt = 0; nt < 4; nt++) {
            pl = fmaf(acc[mt][nt][r], al[nt], pl);
            pr = fmaf(acc[mt][nt][r], ar[nt], pr);
          }
          #pragma unroll
          for (int o = 1; o < 16; o <<= 1) {
            pl += __shfl_xor(pl, o, 64);
            pr += __shfl_xor(pr, o, 64);
          }
          if (row < N_NODES) {
            #pragma unroll
            for (int nt = 0; nt < 4; nt++)
              hbuf[(size_t)row * 256 + col0 + nt * 16 + cn] = f2bf(acc[mt][nt][r]);
            if (cn == 0) {
              el[row * 4 + head] = pl;
              er[row * 4 + head] = pr;
            }
          }
        }
    } else {
      const int rc0 = (nb - 2) * 128 + nh * 64;
      #pragma unroll
      for (int mt = 0; mt < 4; mt++)
        #pragma unroll
        for (int r = 0; r < 4; r++) {
          const int row = r0 + mt * 16 + q * 4 + r;
          if (row < N_NODES)
            #pragma unroll
            for (int nt = 0; nt < 4; nt++) {
              float v = acc[mt][nt][r] + bias[rc0 + nt * 16 + cn];
              resbuf[(size_t)row * 256 + rc0 + nt * 16 + cn] = f2bf(v);
            }
        }
    }
  }
}

// ---------------- CSR build (rows PADDED to multiples of 4) ----------------
__global__ __launch_bounds__(256) void k_scan1(const int* __restrict__ deg,
                                               int* __restrict__ rs, int* __restrict__ bsums)
{
  __shared__ int tmp[256];
  const int t = threadIdx.x;
  const int base = blockIdx.x * 1024 + t * 4;
  int v0 = 0, v1 = 0, v2 = 0, v3 = 0;
  if (base + 0 < N_NODES) v0 = (deg[base + 0] + 3) & ~3;
  if (base + 1 < N_NODES) v1 = (deg[base + 1] + 3) & ~3;
  if (base + 2 < N_NODES) v2 = (deg[base + 2] + 3) & ~3;
  if (base + 3 < N_NODES) v3 = (deg[base + 3] + 3) & ~3;
  const int tsum = v0 + v1 + v2 + v3;
  tmp[t] = tsum;
  __syncthreads();
  for (int o = 1; o < 256; o <<= 1) {
    int x = (t >= o) ? tmp[t - o] : 0;
    __syncthreads();
    tmp[t] += x;
    __syncthreads();
  }
  const int excl = tmp[t] - tsum;
  if (base + 0 < N_NODES) rs[base + 0] = excl;
  if (base + 1 < N_NODES) rs[base + 1] = excl + v0;
  if (base + 2 < N_NODES) rs[base + 2] = excl + v0 + v1;
  if (base + 3 < N_NODES) rs[base + 3] = excl + v0 + v1 + v2;
  if (t == 255) bsums[blockIdx.x] = tmp[t];
}

// finalize padded offsets + fill pad slots with sentinel src
__global__ __launch_bounds__(256) void k_scan3(int* __restrict__ rs,
                                               const int* __restrict__ bsums,
                                               int* __restrict__ cursor,
                                               const int* __restrict__ deg,
                                               int* __restrict__ esrc)
{
  __shared__ int sb[128];
  const int t = threadIdx.x;
  int raw = 0;
  if (t < 128) { raw = (t < 98) ? bsums[t] : 0; sb[t] = raw; }
  __syncthreads();
  for (int o = 1; o < 128; o <<= 1) {
    int x = (t >= o && t < 128) ? sb[t - o] : 0;
    __syncthreads();
    if (t < 128) sb[t] += x;
    __syncthreads();
  }
  if (t < 128) sb[t] -= raw;   // exclusive
  __syncthreads();
  const int i = blockIdx.x * 256 + t;
  if (i < N_NODES) {
    int v = rs[i] + sb[i >> 10];
    rs[i] = v;
    cursor[i] = v;
    const int d = deg[i];
    const int pd = (d + 3) & ~3;
    for (int j = d; j < pd; j++) esrc[v + j] = N_NODES;   // weight-0 dummies
    if (i == N_NODES - 1) rs[N_NODES] = v + pd;
  }
}

__global__ __launch_bounds__(256) void k_scatter(const int* __restrict__ src,
                                                 const int* __restrict__ dst,
                                                 int* __restrict__ cursor,
                                                 int* __restrict__ esrc)
{
  int e = blockIdx.x * 256 + threadIdx.x;
  if (e >= N_EDGES) return;
  int d = dst[e];
  int pos = atomicAdd(&cursor[d], 1);
  esrc[pos] = src[e];
}

// ---------------- fused softmax + aggregation + residual/ELU/head-mean ------
// 2x32 split: lanes 0-31 process even edge of a pair, lanes 32-63 the odd
// edge; each lane covers 8 dims (ushort8 / 16B gather). Depth-4 named-register
// rotation of 2-edge batches (8 edges in flight). No readfirstlane in steady
// state: src ids arrive as a broadcast int2, selected per-half via cndmask.
#define RFL(x) __builtin_amdgcn_readfirstlane(x)

#define GATHER(X) do { \
  const int s_ = (lane & 32) ? sn##X.y : sn##X.x; \
  hv##X = *(const u16x8*)(hbuf + (size_t)s_ * 256 + li8); \
  ev##X = el[s_ * 4 + head]; \
} while (0)

#define PRO(X, B) do { \
  if ((B) < p_end) { sn##X = *(const int2*)(esrc + (B)); GATHER(X); } \
} while (0)

#define COMPUTE(X) do { \
  float e_ = ev##X + ern; \
  e_ = fmaxf(e_, NEG_SLOPE * e_); \
  const float w_ = __expf(e_); \
  ssum += w_; \
  accA.x = fmaf(w_, bf2f(hv##X[0]), accA.x); \
  accA.y = fmaf(w_, bf2f(hv##X[1]), accA.y); \
  accA.z = fmaf(w_, bf2f(hv##X[2]), accA.z); \
  accA.w = fmaf(w_, bf2f(hv##X[3]), accA.w); \
  accB.x = fmaf(w_, bf2f(hv##X[4]), accB.x); \
  accB.y = fmaf(w_, bf2f(hv##X[5]), accB.y); \
  accB.z = fmaf(w_, bf2f(hv##X[6]), accB.z); \
  accB.w = fmaf(w_, bf2f(hv##X[7]), accB.w); \
} while (0)

#define FIN(ND) do { \
  float st_ = ssum + __shfl_xor(ssum, 32, 64); \
  float a0_ = accA.x + __shfl_xor(accA.x, 32, 64); \
  float a1_ = accA.y + __shfl_xor(accA.y, 32, 64); \
  float a2_ = accA.z + __shfl_xor(accA.z, 32, 64); \
  float a3_ = accA.w + __shfl_xor(accA.w, 32, 64); \
  float a4_ = accB.x + __shfl_xor(accB.x, 32, 64); \
  float a5_ = accB.y + __shfl_xor(accB.y, 32, 64); \
  float a6_ = accB.z + __shfl_xor(accB.z, 32, 64); \
  float a7_ = accB.w + __shfl_xor(accB.w, 32, 64); \
  const float inv_ = (st_ > 0.f) ? (1.0f / st_) : 0.f; \
  a0_ = fmaf(a0_, inv_, bf2f(rv_cur[0])); \
  a1_ = fmaf(a1_, inv_, bf2f(rv_cur[1])); \
  a2_ = fmaf(a2_, inv_, bf2f(rv_cur[2])); \
  a3_ = fmaf(a3_, inv_, bf2f(rv_cur[3])); \
  a4_ = fmaf(a4_, inv_, bf2f(rv_cur[4])); \
  a5_ = fmaf(a5_, inv_, bf2f(rv_cur[5])); \
  a6_ = fmaf(a6_, inv_, bf2f(rv_cur[6])); \
  a7_ = fmaf(a7_, inv_, bf2f(rv_cur[7])); \
  a0_ = (a0_ > 0.f) ? a0_ : (__expf(a0_) - 1.f); \
  a1_ = (a1_ > 0.f) ? a1_ : (__expf(a1_) - 1.f); \
  a2_ = (a2_ > 0.f) ? a2_ : (__expf(a2_) - 1.f); \
  a3_ = (a3_ > 0.f) ? a3_ : (__expf(a3_) - 1.f); \
  a4_ = (a4_ > 0.f) ? a4_ : (__expf(a4_) - 1.f); \
  a5_ = (a5_ > 0.f) ? a5_ : (__expf(a5_) - 1.f); \
  a6_ = (a6_ > 0.f) ? a6_ : (__expf(a6_) - 1.f); \
  a7_ = (a7_ > 0.f) ? a7_ : (__expf(a7_) - 1.f); \
  a0_ += __shfl_xor(a0_, 8, 64);  a0_ += __shfl_xor(a0_, 16, 64); \
  a1_ += __shfl_xor(a1_, 8, 64);  a1_ += __shfl_xor(a1_, 16, 64); \
  a2_ += __shfl_xor(a2_, 8, 64);  a2_ += __shfl_xor(a2_, 16, 64); \
  a3_ += __shfl_xor(a3_, 8, 64);  a3_ += __shfl_xor(a3_, 16, 64); \
  a4_ += __shfl_xor(a4_, 8, 64);  a4_ += __shfl_xor(a4_, 16, 64); \
  a5_ += __shfl_xor(a5_, 8, 64);  a5_ += __shfl_xor(a5_, 16, 64); \
  a6_ += __shfl_xor(a6_, 8, 64);  a6_ += __shfl_xor(a6_, 16, 64); \
  a7_ += __shfl_xor(a7_, 8, 64);  a7_ += __shfl_xor(a7_, 16, 64); \
  if (lane < 8) { \
    float4 o1_, o2_; \
    o1_.x = a0_ * 0.25f; o1_.y = a1_ * 0.25f; o1_.z = a2_ * 0.25f; o1_.w = a3_ * 0.25f; \
    o2_.x = a4_ * 0.25f; o2_.y = a5_ * 0.25f; o2_.z = a6_ * 0.25f; o2_.w = a7_ * 0.25f; \
    *(float4*)(out + (size_t)(ND) * 64 + li8) = o1_; \
    *(float4*)(out + (size_t)(ND) * 64 + li8 + 4) = o2_; \
  } \
} while (0)

#define BOUNDARY() \
  while (p == nend) { \
    FIN(nu); \
    accA.x=0.f; accA.y=0.f; accA.z=0.f; accA.w=0.f; \
    accB.x=0.f; accB.y=0.f; accB.z=0.f; accB.w=0.f; ssum = 0.f; \
    nu++; \
    nend = nendN; ern = ernN; rv_cur = rvN; \
    const int f1_ = (nu + 1 < N_NODES) ? (nu + 1) : (N_NODES - 1); \
    const int f2_ = (nu + 2 <= N_NODES) ? (nu + 2) : N_NODES; \
    nendN = RFL(rs[f2_]); \
    ernN = er[f1_ * 4 + head]; \
    rvN = *(const u16x8*)(resbuf + (size_t)f1_ * 256 + li8); \
  }

#define STEP(CUR, NXT) do { \
  if (p + 6 < p_end) GATHER(NXT); \
  if (p + 8 < p_end) sn##CUR = *(const int2*)(esrc + p + 8); \
  BOUNDARY(); \
  COMPUTE(CUR); \
} while (0)

__global__ __launch_bounds__(256, 4) void k_agg(
    const unsigned short* __restrict__ hbuf, const unsigned short* __restrict__ resbuf,
    const float* __restrict__ el, const float* __restrict__ er,
    const int* __restrict__ rs, const int* __restrict__ esrc,
    float* __restrict__ out)
{
  const int lane = threadIdx.x & 63;
  const int li = lane & 31;
  const int head = li >> 3;          // 4 heads x 8 lanes per 32-half
  const int li8 = li * 8;            // 8 dims per lane
  const int wid = blockIdx.x * 4 + (threadIdx.x >> 6);
  const int nW = gridDim.x * 4;

  const int n0 = (int)(((long long)wid * N_NODES) / nW);
  const int n1 = (int)(((long long)(wid + 1) * N_NODES) / nW);
  if (n0 >= n1) return;

  int nu = RFL(n0);
  const int p_end = RFL(rs[n1]);
  int nend = RFL(rs[nu + 1]);
  int f1 = (nu + 1 < N_NODES) ? (nu + 1) : (N_NODES - 1);
  int f2 = (nu + 2 <= N_NODES) ? (nu + 2) : N_NODES;
  int nendN = RFL(rs[f2]);
  float ern  = er[nu * 4 + head];
  float ernN = er[f1 * 4 + head];
  u16x8 rv_cur = *(const u16x8*)(resbuf + (size_t)nu * 256 + li8);
  u16x8 rvN    = *(const u16x8*)(resbuf + (size_t)f1 * 256 + li8);

  float4 accA = make_float4(0.f, 0.f, 0.f, 0.f);
  float4 accB = make_float4(0.f, 0.f, 0.f, 0.f);
  float ssum = 0.f;

  int2 snA, snB, snC, snD;
  float evA, evB, evC, evD;
  u16x8 hvA, hvB, hvC, hvD;

  int p = RFL(rs[nu]);               // multiple of 4
  const int ph = (p >> 1) & 3;       // 0 or 2: entry slot
  if (ph == 0) {
    PRO(A, p); PRO(B, p + 2); PRO(C, p + 4);
    if (p + 6 < p_end) snD = *(const int2*)(esrc + p + 6);
  } else {
    PRO(C, p); PRO(D, p + 2); PRO(A, p + 4);
    if (p + 6 < p_end) snB = *(const int2*)(esrc + p + 6);
  }

  if (ph == 2 && p < p_end) {
    STEP(C, B); p += 2;
    if (p < p_end) { STEP(D, C); p += 2; }
  }
  while (p < p_end) {
    STEP(A, D); p += 2; if (p >= p_end) break;
    STEP(B, A); p += 2; if (p >= p_end) break;
    STEP(C, B); p += 2; if (p >= p_end) break;
    STEP(D, C); p += 2;
  }

  // drain: finalize last node + trailing zero-degree nodes
  while (nu < n1) {
    FIN(nu);
    accA.x=0.f; accA.y=0.f; accA.z=0.f; accA.w=0.f;
    accB.x=0.f; accB.y=0.f; accB.z=0.f; accB.w=0.f; ssum = 0.f;
    nu++;
    if (nu < n1) rv_cur = *(const u16x8*)(resbuf + (size_t)nu * 256 + li8);
  }
}

// ---------------- BN stats over out (separate small pass) ----------------
__global__ __launch_bounds__(256) void k_bn_stats(const float* __restrict__ out,
                                                  float* __restrict__ bn)
{
  const int t = threadIdx.x;
  const int c4 = (t & 15) * 4;
  const int rg = t >> 4;
  float4 s = make_float4(0.f, 0.f, 0.f, 0.f);
  float4 q = make_float4(0.f, 0.f, 0.f, 0.f);
  for (int row = blockIdx.x * 16 + rg; row < N_NODES; row += gridDim.x * 16) {
    float4 v = *(const float4*)(out + (size_t)row * 64 + c4);
    s.x += v.x; s.y += v.y; s.z += v.z; s.w += v.w;
    q.x += v.x * v.x; q.y += v.y * v.y; q.z += v.z * v.z; q.w += v.w * v.w;
  }
  __shared__ float ls[64], lq[64];
  if (t < 64) { ls[t] = 0.f; lq[t] = 0.f; }
  __syncthreads();
  atomicAdd(&ls[c4 + 0], s.x); atomicAdd(&ls[c4 + 1], s.y);
  atomicAdd(&ls[c4 + 2], s.z); atomicAdd(&ls[c4 + 3], s.w);
  atomicAdd(&lq[c4 + 0], q.x); atomicAdd(&lq[c4 + 1], q.y);
  atomicAdd(&lq[c4 + 2], q.z); atomicAdd(&lq[c4 + 3], q.w);
  __syncthreads();
  if (t < 64) {
    atomicAdd(&bn[t], ls[t]);
    atomicAdd(&bn[64 + t], lq[t]);
  }
}

// ---------------- batchnorm apply ----------------
__global__ __launch_bounds__(256) void k_bn_apply(float* __restrict__ out,
                                                  const float* __restrict__ bn,
                                                  const float* __restrict__ gamma,
                                                  const float* __restrict__ beta)
{
  __shared__ float sc[64], sh[64];
  const int t = threadIdx.x;
  if (t < 64) {
    float mean = bn[t] * (1.0f / N_NODES);
    float var = bn[64 + t] * (1.0f / N_NODES) - mean * mean;
    float s = gamma[t] * rsqrtf(var + BN_EPS);
    sc[t] = s;
    sh[t] = beta[t] - mean * s;
  }
  __syncthreads();
  const int i = blockIdx.x * 256 + t;
  if (i >= N_NODES * 16) return;
  const int d0 = (i & 15) * 4;
  float4 v = *(float4*)(out + (size_t)i * 4);
  v.x = fmaf(v.x, sc[d0 + 0], sh[d0 + 0]);
  v.y = fmaf(v.y, sc[d0 + 1], sh[d0 + 1]);
  v.z = fmaf(v.z, sc[d0 + 2], sh[d0 + 2]);
  v.w = fmaf(v.w, sc[d0 + 3], sh[d0 + 3]);
  *(float4*)(out + (size_t)i * 4) = v;
}

extern "C" void kernel_launch(void* const* d_in, const int* in_sizes, int n_in,
                              void* d_out, int out_size, void* d_ws, size_t ws_size,
                              hipStream_t stream)
{
  const float* feats  = (const float*)d_in[0];
  const int*   src    = (const int*)d_in[1];
  const int*   dst    = (const int*)d_in[2];
  const float* fc_w   = (const float*)d_in[3];
  const float* attn_l = (const float*)d_in[4];
  const float* attn_r = (const float*)d_in[5];
  const float* res_w  = (const float*)d_in[6];
  const float* bias   = (const float*)d_in[7];
  const float* gamma  = (const float*)d_in[8];
  const float* beta   = (const float*)d_in[9];

  char* ws = (char*)d_ws;
  unsigned short* Ab     = (unsigned short*)(ws + OFF_AB);
  unsigned short* Bb     = (unsigned short*)(ws + OFF_BB);
  unsigned short* hbuf   = (unsigned short*)(ws + OFF_H);
  unsigned short* resbuf = (unsigned short*)(ws + OFF_RES);
  float* elb    = (float*)(ws + OFF_EL);
  float* erb    = (float*)(ws + OFF_ER);
  int*   deg    = (int*)(ws + OFF_DEG);
  int*   rsb    = (int*)(ws + OFF_RS);
  int*   curb   = (int*)(ws + OFF_CUR);
  int*   esrc   = (int*)(ws + OFF_ESRC);
  int*   bsums  = (int*)(ws + OFF_BS);
  float* bnb    = (float*)(ws + OFF_BN);
  float* outp   = (float*)d_out;

  hipMemsetAsync(deg, 0, N_NODES * sizeof(int), stream);
  hipMemsetAsync(bnb, 0, 128 * sizeof(float), stream);

  k_pre<<<12539, 256, 0, stream>>>(feats, fc_w, res_w, dst, Ab, Bb, deg, hbuf, elb);
  k_mm<<<dim3(782, 2), 256, 0, stream>>>(Ab, Bb, bias, attn_l, attn_r,
                                         hbuf, resbuf, elb, erb);
  k_scan1<<<98, 256, 0, stream>>>(deg, rsb, bsums);
  k_scan3<<<391, 256, 0, stream>>>(rsb, bsums, curb, deg, esrc);
  k_scatter<<<6250, 256, 0, stream>>>(src, dst, curb, esrc);
  k_agg<<<2048, 256, 0, stream>>>(hbuf, resbuf, elb, erb, rsb, esrc, outp);
  k_bn_stats<<<256, 256, 0, stream>>>(outp, bnb);
  k_bn_apply<<<6250, 256, 0, stream>>>(outp, bnb, gamma, beta);
}

// Round 4
// 520.814 us; speedup vs baseline: 1.0117x; 1.0117x over previous
//
#include <hip/hip_runtime.h>

#define N_NODES 100000
#define N_EDGES 1600000
#define NEG_SLOPE 0.2f
#define BN_EPS 1e-5f

typedef __attribute__((ext_vector_type(8))) short short8;
typedef __attribute__((ext_vector_type(4))) float floatx4;
typedef __attribute__((ext_vector_type(8))) unsigned short u16x8;

// ---------------- workspace layout (bytes) ----------------
static const size_t OFF_AB   = 0;            // feats bf16 fragment-ordered [N_PAD,128]
static const size_t OFF_BB   = 25624576;     // weights bf16 fragment-ordered [512,128]
static const size_t OFF_H    = 25755648;     // h bf16 [N+1,256] (row N = sentinel zeros)
static const size_t OFF_RES  = 76956672;     // res+bias bf16 [N,256]
static const size_t OFF_EL   = 128156672;    // el [N+1,4] f32 (row N = -1e30 sentinel)
static const size_t OFF_ER   = 129757184;    // er [N,4] f32
static const size_t OFF_DEG  = 131357184;    // deg [N] i32
static const size_t OFF_RS   = 131757184;    // padded row_start [N+1] i32
static const size_t OFF_CUR  = 132157568;    // cursor [N] i32
static const size_t OFF_ESRC = 132557568;    // padded edge src ids [<=2.0M] i32
static const size_t OFF_BS   = 142157568;    // block sums [128] i32
static const size_t OFF_BN   = 142158080;    // bn accum [128] f32
// total ~142.2 MB

__device__ __forceinline__ unsigned short f2bf(float x) {
  unsigned int u = __float_as_uint(x);
  unsigned int r = (u + 0x7fffu + ((u >> 16) & 1u)) >> 16;   // RNE
  return (unsigned short)r;
}
__device__ __forceinline__ float bf2f(unsigned short u) {
  return __uint_as_float(((unsigned int)u) << 16);
}

// ---------------- fused pre-pass: cvt_a | edge count | cvt_w | sentinels ----
__global__ __launch_bounds__(256) void k_pre(
    const float* __restrict__ feats, const float* __restrict__ fc_w,
    const float* __restrict__ res_w, const int* __restrict__ dst,
    unsigned short* __restrict__ Ab, unsigned short* __restrict__ Bb,
    int* __restrict__ deg, unsigned short* __restrict__ hbuf,
    float* __restrict__ el)
{
  const int b = blockIdx.x;
  if (b < 6256) {                                // ---- cvt_a: N_PAD*16 chunks
    int c = b * 256 + threadIdx.x;
    int r = c >> 4, j = c & 15;
    unsigned short v[8];
    if (r < N_NODES) {
      const float* p = feats + (size_t)r * 128 + j * 8;
      float4 a = *(const float4*)p, bb = *(const float4*)(p + 4);
      v[0]=f2bf(a.x); v[1]=f2bf(a.y); v[2]=f2bf(a.z); v[3]=f2bf(a.w);
      v[4]=f2bf(bb.x); v[5]=f2bf(bb.y); v[6]=f2bf(bb.z); v[7]=f2bf(bb.w);
    } else {
      for (int i = 0; i < 8; i++) v[i] = 0;
    }
    size_t idx = (size_t)(r >> 7) * 2048 + ((r >> 4) & 7) * 256 + (j >> 2) * 64
               + (r & 15) + 16 * (j & 3);
    *(short8*)(Ab + idx * 8) = *(short8*)v;
  } else if (b < 12506) {                        // ---- count degrees
    int e = (b - 6256) * 256 + threadIdx.x;
    if (e < N_EDGES) atomicAdd(&deg[dst[e]], 1);
  } else if (b < 12538) {                        // ---- cvt_w: 8192 chunks
    int c = (b - 12506) * 256 + threadIdx.x;
    int n = c >> 4, j = c & 15;
    const float* W = (n < 256) ? (fc_w + (size_t)n * 128) : (res_w + (size_t)(n - 256) * 128);
    const float* p = W + j * 8;
    float4 a = *(const float4*)p, bb = *(const float4*)(p + 4);
    unsigned short v[8];
    v[0]=f2bf(a.x); v[1]=f2bf(a.y); v[2]=f2bf(a.z); v[3]=f2bf(a.w);
    v[4]=f2bf(bb.x); v[5]=f2bf(bb.y); v[6]=f2bf(bb.z); v[7]=f2bf(bb.w);
    size_t idx = (size_t)(n >> 7) * 2048 + ((n >> 4) & 7) * 256 + (j >> 2) * 64
               + (n & 15) + 16 * (j & 3);
    *(short8*)(Bb + idx * 8) = *(short8*)v;
  } else {                                       // ---- sentinel row init
    const int t = threadIdx.x;
    hbuf[(size_t)N_NODES * 256 + t] = 0;         // zero h row for dummy src
    if (t < 4) el[N_NODES * 4 + t] = -1e30f;     // weight-0 logit for dummy src
  }
}

// ---------------- MFMA projection + fused el/er -----------------------------
// grid (782, 2): block stages A once, inner loop computes h-half (nb=y) and
// res-half (nb=y+2) -> A fetched 2x instead of 4x.
__global__ __launch_bounds__(256) void k_mm(
    const unsigned short* __restrict__ Ab, const unsigned short* __restrict__ Bb,
    const float* __restrict__ bias, const float* __restrict__ attn_l,
    const float* __restrict__ attn_r,
    unsigned short* __restrict__ hbuf, unsigned short* __restrict__ resbuf,
    float* __restrict__ el, float* __restrict__ er)
{
  __shared__ unsigned short sA[16384];  // 32 KB, fragment-ordered A block
  const int tid = threadIdx.x;
  const int w = tid >> 6, L = tid & 63;
  const int blk = blockIdx.x;

  {  // stage A: contiguous 32 KB, global_load_lds width 16
    const unsigned short* ga = Ab + (size_t)blk * 16384;
    #pragma unroll
    for (int i = 0; i < 8; i++) {
      int off = (i * 256 + w * 64) * 8;
      __builtin_amdgcn_global_load_lds(
          (const __attribute__((address_space(1))) unsigned int*)(ga + off + L * 8),
          (__attribute__((address_space(3))) unsigned int*)(sA + off),
          16, 0, 0);
    }
  }
  const int mh = w & 1, nh = w >> 1;
  __syncthreads();

  for (int wb = 0; wb < 2; ++wb) {
    const int nb = blockIdx.y + wb * 2;
    floatx4 acc[4][4] = {};
    const unsigned short* gb = Bb + ((size_t)nb * 2048 + nh * 4 * 256) * 8 + L * 8;
    #pragma unroll
    for (int s = 0; s < 4; s++) {
      short8 a[4], b[4];
      #pragma unroll
      for (int t = 0; t < 4; t++)
        a[t] = *(const short8*)(sA + ((mh * 4 + t) * 256 + s * 64 + L) * 8);
      #pragma unroll
      for (int t = 0; t < 4; t++)
        b[t] = *(const short8*)(gb + ((size_t)t * 256 + s * 64) * 8);
      #pragma unroll
      for (int mt = 0; mt < 4; mt++)
        #pragma unroll
        for (int nt = 0; nt < 4; nt++)
          acc[mt][nt] = __builtin_amdgcn_mfma_f32_16x16x32_bf16(a[mt], b[nt], acc[mt][nt], 0, 0, 0);
    }

    const int q = L >> 4, cn = L & 15;
    const int r0 = blk * 128 + mh * 64;
    if (nb < 2) {
      const int head = nb * 2 + nh;            // this wave owns one full head
      const int col0 = nb * 128 + nh * 64;
      float al[4], ar[4];
      #pragma unroll
      for (int nt = 0; nt < 4; nt++) {
        al[nt] = attn_l[head * 64 + nt * 16 + cn];
        ar[nt] = attn_r[head * 64 + nt * 16 + cn];
      }
      #pragma unroll
      for (int mt = 0; mt < 4; mt++)
        #pragma unroll
        for (int r = 0; r < 4; r++) {
          const int row = r0 + mt * 16 + q * 4 + r;
          float pl = 0.f, pr = 0.f;
          #pragma unroll
          for (int nt = 0; nt < 4; nt++) {
            pl = fmaf(acc[mt][nt][r], al[nt], pl);
            pr = fmaf(acc[mt][nt][r], ar[nt], pr);
          }
          #pragma unroll
          for (int o = 1; o < 16; o <<= 1) {
            pl += __shfl_xor(pl, o, 64);
            pr += __shfl_xor(pr, o, 64);
          }
          if (row < N_NODES) {
            #pragma unroll
            for (int nt = 0; nt < 4; nt++)
              hbuf[(size_t)row * 256 + col0 + nt * 16 + cn] = f2bf(acc[mt][nt][r]);
            if (cn == 0) {
              el[row * 4 + head] = pl;
              er[row * 4 + head] = pr;
            }
          }
        }
    } else {
      const int rc0 = (nb - 2) * 128 + nh * 64;
      #pragma unroll
      for (int mt = 0; mt < 4; mt++)
        #pragma unroll
        for (int r = 0; r < 4; r++) {
          const int row = r0 + mt * 16 + q * 4 + r;
          if (row < N_NODES)
            #pragma unroll
            for (int nt = 0; nt < 4; nt++) {
              float v = acc[mt][nt][r] + bias[rc0 + nt * 16 + cn];
              resbuf[(size_t)row * 256 + rc0 + nt * 16 + cn] = f2bf(v);
            }
        }
    }
  }
}

// ---------------- CSR build (rows PADDED to multiples of 4) ----------------
__global__ __launch_bounds__(256) void k_scan1(const int* __restrict__ deg,
                                               int* __restrict__ rs, int* __restrict__ bsums)
{
  __shared__ int tmp[256];
  const int t = threadIdx.x;
  const int base = blockIdx.x * 1024 + t * 4;
  int v0 = 0, v1 = 0, v2 = 0, v3 = 0;
  if (base + 0 < N_NODES) v0 = (deg[base + 0] + 3) & ~3;
  if (base + 1 < N_NODES) v1 = (deg[base + 1] + 3) & ~3;
  if (base + 2 < N_NODES) v2 = (deg[base + 2] + 3) & ~3;
  if (base + 3 < N_NODES) v3 = (deg[base + 3] + 3) & ~3;
  const int tsum = v0 + v1 + v2 + v3;
  tmp[t] = tsum;
  __syncthreads();
  for (int o = 1; o < 256; o <<= 1) {
    int x = (t >= o) ? tmp[t - o] : 0;
    __syncthreads();
    tmp[t] += x;
    __syncthreads();
  }
  const int excl = tmp[t] - tsum;
  if (base + 0 < N_NODES) rs[base + 0] = excl;
  if (base + 1 < N_NODES) rs[base + 1] = excl + v0;
  if (base + 2 < N_NODES) rs[base + 2] = excl + v0 + v1;
  if (base + 3 < N_NODES) rs[base + 3] = excl + v0 + v1 + v2;
  if (t == 255) bsums[blockIdx.x] = tmp[t];
}

// finalize padded offsets + fill pad slots with sentinel src
__global__ __launch_bounds__(256) void k_scan3(int* __restrict__ rs,
                                               const int* __restrict__ bsums,
                                               int* __restrict__ cursor,
                                               const int* __restrict__ deg,
                                               int* __restrict__ esrc)
{
  __shared__ int sb[128];
  const int t = threadIdx.x;
  int raw = 0;
  if (t < 128) { raw = (t < 98) ? bsums[t] : 0; sb[t] = raw; }
  __syncthreads();
  for (int o = 1; o < 128; o <<= 1) {
    int x = (t >= o && t < 128) ? sb[t - o] : 0;
    __syncthreads();
    if (t < 128) sb[t] += x;
    __syncthreads();
  }
  if (t < 128) sb[t] -= raw;   // exclusive
  __syncthreads();
  const int i = blockIdx.x * 256 + t;
  if (i < N_NODES) {
    int v = rs[i] + sb[i >> 10];
    rs[i] = v;
    cursor[i] = v;
    const int d = deg[i];
    const int pd = (d + 3) & ~3;
    for (int j = d; j < pd; j++) esrc[v + j] = N_NODES;   // weight-0 dummies
    if (i == N_NODES - 1) rs[N_NODES] = v + pd;
  }
}

__global__ __launch_bounds__(256) void k_scatter(const int* __restrict__ src,
                                                 const int* __restrict__ dst,
                                                 int* __restrict__ cursor,
                                                 int* __restrict__ esrc)
{
  int e = blockIdx.x * 256 + threadIdx.x;
  if (e >= N_EDGES) return;
  int d = dst[e];
  int pos = atomicAdd(&cursor[d], 1);
  esrc[pos] = src[e];
}

// ---------------- fused softmax + aggregation + residual/ELU/head-mean ------
// 2x32 split (lanes 0-31 even edge, 32-63 odd edge; 8 dims/lane, 16B gather)
// with DEPTH-8 named-register rotation: gathers in flight for 6 batches
// (12 edges), src ids 8 batches ahead. Round-2/3 A/B showed MLP, not VALU
// issue, is binding -> this keeps round-3's low op count at 2x the depth.
#define RFL(x) __builtin_amdgcn_readfirstlane(x)

#define GATHER(X) do { \
  const int s_ = (lane & 32) ? sn##X.y : sn##X.x; \
  hv##X = *(const u16x8*)(hbuf + (size_t)s_ * 256 + li8); \
  ev##X = el[s_ * 4 + head]; \
} while (0)

#define PRO(X, B) do { \
  if ((B) < p_end) { sn##X = *(const int2*)(esrc + (B)); GATHER(X); } \
} while (0)

#define COMPUTE(X) do { \
  float e_ = ev##X + ern; \
  e_ = fmaxf(e_, NEG_SLOPE * e_); \
  const float w_ = __expf(e_); \
  ssum += w_; \
  accA.x = fmaf(w_, bf2f(hv##X[0]), accA.x); \
  accA.y = fmaf(w_, bf2f(hv##X[1]), accA.y); \
  accA.z = fmaf(w_, bf2f(hv##X[2]), accA.z); \
  accA.w = fmaf(w_, bf2f(hv##X[3]), accA.w); \
  accB.x = fmaf(w_, bf2f(hv##X[4]), accB.x); \
  accB.y = fmaf(w_, bf2f(hv##X[5]), accB.y); \
  accB.z = fmaf(w_, bf2f(hv##X[6]), accB.z); \
  accB.w = fmaf(w_, bf2f(hv##X[7]), accB.w); \
} while (0)

#define FIN(ND) do { \
  float st_ = ssum + __shfl_xor(ssum, 32, 64); \
  float a0_ = accA.x + __shfl_xor(accA.x, 32, 64); \
  float a1_ = accA.y + __shfl_xor(accA.y, 32, 64); \
  float a2_ = accA.z + __shfl_xor(accA.z, 32, 64); \
  float a3_ = accA.w + __shfl_xor(accA.w, 32, 64); \
  float a4_ = accB.x + __shfl_xor(accB.x, 32, 64); \
  float a5_ = accB.y + __shfl_xor(accB.y, 32, 64); \
  float a6_ = accB.z + __shfl_xor(accB.z, 32, 64); \
  float a7_ = accB.w + __shfl_xor(accB.w, 32, 64); \
  const float inv_ = (st_ > 0.f) ? (1.0f / st_) : 0.f; \
  a0_ = fmaf(a0_, inv_, bf2f(rv_cur[0])); \
  a1_ = fmaf(a1_, inv_, bf2f(rv_cur[1])); \
  a2_ = fmaf(a2_, inv_, bf2f(rv_cur[2])); \
  a3_ = fmaf(a3_, inv_, bf2f(rv_cur[3])); \
  a4_ = fmaf(a4_, inv_, bf2f(rv_cur[4])); \
  a5_ = fmaf(a5_, inv_, bf2f(rv_cur[5])); \
  a6_ = fmaf(a6_, inv_, bf2f(rv_cur[6])); \
  a7_ = fmaf(a7_, inv_, bf2f(rv_cur[7])); \
  a0_ = (a0_ > 0.f) ? a0_ : (__expf(a0_) - 1.f); \
  a1_ = (a1_ > 0.f) ? a1_ : (__expf(a1_) - 1.f); \
  a2_ = (a2_ > 0.f) ? a2_ : (__expf(a2_) - 1.f); \
  a3_ = (a3_ > 0.f) ? a3_ : (__expf(a3_) - 1.f); \
  a4_ = (a4_ > 0.f) ? a4_ : (__expf(a4_) - 1.f); \
  a5_ = (a5_ > 0.f) ? a5_ : (__expf(a5_) - 1.f); \
  a6_ = (a6_ > 0.f) ? a6_ : (__expf(a6_) - 1.f); \
  a7_ = (a7_ > 0.f) ? a7_ : (__expf(a7_) - 1.f); \
  a0_ += __shfl_xor(a0_, 8, 64);  a0_ += __shfl_xor(a0_, 16, 64); \
  a1_ += __shfl_xor(a1_, 8, 64);  a1_ += __shfl_xor(a1_, 16, 64); \
  a2_ += __shfl_xor(a2_, 8, 64);  a2_ += __shfl_xor(a2_, 16, 64); \
  a3_ += __shfl_xor(a3_, 8, 64);  a3_ += __shfl_xor(a3_, 16, 64); \
  a4_ += __shfl_xor(a4_, 8, 64);  a4_ += __shfl_xor(a4_, 16, 64); \
  a5_ += __shfl_xor(a5_, 8, 64);  a5_ += __shfl_xor(a5_, 16, 64); \
  a6_ += __shfl_xor(a6_, 8, 64);  a6_ += __shfl_xor(a6_, 16, 64); \
  a7_ += __shfl_xor(a7_, 8, 64);  a7_ += __shfl_xor(a7_, 16, 64); \
  if (lane < 8) { \
    float4 o1_, o2_; \
    o1_.x = a0_ * 0.25f; o1_.y = a1_ * 0.25f; o1_.z = a2_ * 0.25f; o1_.w = a3_ * 0.25f; \
    o2_.x = a4_ * 0.25f; o2_.y = a5_ * 0.25f; o2_.z = a6_ * 0.25f; o2_.w = a7_ * 0.25f; \
    *(float4*)(out + (size_t)(ND) * 64 + li8) = o1_; \
    *(float4*)(out + (size_t)(ND) * 64 + li8 + 4) = o2_; \
  } \
} while (0)

#define BOUNDARY() \
  while (p == nend) { \
    FIN(nu); \
    accA.x=0.f; accA.y=0.f; accA.z=0.f; accA.w=0.f; \
    accB.x=0.f; accB.y=0.f; accB.z=0.f; accB.w=0.f; ssum = 0.f; \
    nu++; \
    nend = nendN; ern = ernN; rv_cur = rvN; \
    const int f1_ = (nu + 1 < N_NODES) ? (nu + 1) : (N_NODES - 1); \
    const int f2_ = (nu + 2 <= N_NODES) ? (nu + 2) : N_NODES; \
    nendN = RFL(rs[f2_]); \
    ernN = er[f1_ * 4 + head]; \
    rvN = *(const u16x8*)(resbuf + (size_t)f1_ * 256 + li8); \
  }

// STEP(CUR, GAT): compute batch p (slot CUR), gather batch p+12 (slot GAT =
// CUR+6 mod 8, sn already loaded), load src ids for batch p+16 (slot CUR).
#define STEP(CUR, GAT) do { \
  if (p + 12 < p_end) GATHER(GAT); \
  if (p + 16 < p_end) sn##CUR = *(const int2*)(esrc + p + 16); \
  BOUNDARY(); \
  COMPUTE(CUR); \
} while (0)

__global__ __launch_bounds__(256, 4) void k_agg(
    const unsigned short* __restrict__ hbuf, const unsigned short* __restrict__ resbuf,
    const float* __restrict__ el, const float* __restrict__ er,
    const int* __restrict__ rs, const int* __restrict__ esrc,
    float* __restrict__ out)
{
  const int lane = threadIdx.x & 63;
  const int li = lane & 31;
  const int head = li >> 3;          // 4 heads x 8 lanes per 32-half
  const int li8 = li * 8;            // 8 dims per lane
  const int wid = blockIdx.x * 4 + (threadIdx.x >> 6);
  const int nW = gridDim.x * 4;

  const int n0 = (int)(((long long)wid * N_NODES) / nW);
  const int n1 = (int)(((long long)(wid + 1) * N_NODES) / nW);
  if (n0 >= n1) return;

  int nu = RFL(n0);
  const int p_end = RFL(rs[n1]);
  int nend = RFL(rs[nu + 1]);
  int f1 = (nu + 1 < N_NODES) ? (nu + 1) : (N_NODES - 1);
  int f2 = (nu + 2 <= N_NODES) ? (nu + 2) : N_NODES;
  int nendN = RFL(rs[f2]);
  float ern  = er[nu * 4 + head];
  float ernN = er[f1 * 4 + head];
  u16x8 rv_cur = *(const u16x8*)(resbuf + (size_t)nu * 256 + li8);
  u16x8 rvN    = *(const u16x8*)(resbuf + (size_t)f1 * 256 + li8);

  float4 accA = make_float4(0.f, 0.f, 0.f, 0.f);
  float4 accB = make_float4(0.f, 0.f, 0.f, 0.f);
  float ssum = 0.f;

  int2 snA, snB, snC, snD, snE, snF, snG, snH;
  float evA, evB, evC, evD, evE, evF, evG, evH;
  u16x8 hvA, hvB, hvC, hvD, hvE, hvF, hvG, hvH;

  int p = RFL(rs[nu]);               // multiple of 4 (slots are relative)
  PRO(A, p);      PRO(B, p + 2);  PRO(C, p + 4);  PRO(D, p + 6);
  PRO(E, p + 8);  PRO(F, p + 10);
  if (p + 12 < p_end) snG = *(const int2*)(esrc + p + 12);
  if (p + 14 < p_end) snH = *(const int2*)(esrc + p + 14);

  while (p < p_end) {
    STEP(A, G); p += 2; if (p >= p_end) break;
    STEP(B, H); p += 2; if (p >= p_end) break;
    STEP(C, A); p += 2; if (p >= p_end) break;
    STEP(D, B); p += 2; if (p >= p_end) break;
    STEP(E, C); p += 2; if (p >= p_end) break;
    STEP(F, D); p += 2; if (p >= p_end) break;
    STEP(G, E); p += 2; if (p >= p_end) break;
    STEP(H, F); p += 2;
  }

  // drain: finalize last node + trailing zero-degree nodes
  while (nu < n1) {
    FIN(nu);
    accA.x=0.f; accA.y=0.f; accA.z=0.f; accA.w=0.f;
    accB.x=0.f; accB.y=0.f; accB.z=0.f; accB.w=0.f; ssum = 0.f;
    nu++;
    if (nu < n1) rv_cur = *(const u16x8*)(resbuf + (size_t)nu * 256 + li8);
  }
}

// ---------------- BN stats over out (separate small pass) ----------------
__global__ __launch_bounds__(256) void k_bn_stats(const float* __restrict__ out,
                                                  float* __restrict__ bn)
{
  const int t = threadIdx.x;
  const int c4 = (t & 15) * 4;
  const int rg = t >> 4;
  float4 s = make_float4(0.f, 0.f, 0.f, 0.f);
  float4 q = make_float4(0.f, 0.f, 0.f, 0.f);
  for (int row = blockIdx.x * 16 + rg; row < N_NODES; row += gridDim.x * 16) {
    float4 v = *(const float4*)(out + (size_t)row * 64 + c4);
    s.x += v.x; s.y += v.y; s.z += v.z; s.w += v.w;
    q.x += v.x * v.x; q.y += v.y * v.y; q.z += v.z * v.z; q.w += v.w * v.w;
  }
  __shared__ float ls[64], lq[64];
  if (t < 64) { ls[t] = 0.f; lq[t] = 0.f; }
  __syncthreads();
  atomicAdd(&ls[c4 + 0], s.x); atomicAdd(&ls[c4 + 1], s.y);
  atomicAdd(&ls[c4 + 2], s.z); atomicAdd(&ls[c4 + 3], s.w);
  atomicAdd(&lq[c4 + 0], q.x); atomicAdd(&lq[c4 + 1], q.y);
  atomicAdd(&lq[c4 + 2], q.z); atomicAdd(&lq[c4 + 3], q.w);
  __syncthreads();
  if (t < 64) {
    atomicAdd(&bn[t], ls[t]);
    atomicAdd(&bn[64 + t], lq[t]);
  }
}

// ---------------- batchnorm apply ----------------
__global__ __launch_bounds__(256) void k_bn_apply(float* __restrict__ out,
                                                  const float* __restrict__ bn,
                                                  const float* __restrict__ gamma,
                                                  const float* __restrict__ beta)
{
  __shared__ float sc[64], sh[64];
  const int t = threadIdx.x;
  if (t < 64) {
    float mean = bn[t] * (1.0f / N_NODES);
    float var = bn[64 + t] * (1.0f / N_NODES) - mean * mean;
    float s = gamma[t] * rsqrtf(var + BN_EPS);
    sc[t] = s;
    sh[t] = beta[t] - mean * s;
  }
  __syncthreads();
  const int i = blockIdx.x * 256 + t;
  if (i >= N_NODES * 16) return;
  const int d0 = (i & 15) * 4;
  float4 v = *(float4*)(out + (size_t)i * 4);
  v.x = fmaf(v.x, sc[d0 + 0], sh[d0 + 0]);
  v.y = fmaf(v.y, sc[d0 + 1], sh[d0 + 1]);
  v.z = fmaf(v.z, sc[d0 + 2], sh[d0 + 2]);
  v.w = fmaf(v.w, sc[d0 + 3], sh[d0 + 3]);
  *(float4*)(out + (size_t)i * 4) = v;
}

extern "C" void kernel_launch(void* const* d_in, const int* in_sizes, int n_in,
                              void* d_out, int out_size, void* d_ws, size_t ws_size,
                              hipStream_t stream)
{
  const float* feats  = (const float*)d_in[0];
  const int*   src    = (const int*)d_in[1];
  const int*   dst    = (const int*)d_in[2];
  const float* fc_w   = (const float*)d_in[3];
  const float* attn_l = (const float*)d_in[4];
  const float* attn_r = (const float*)d_in[5];
  const float* res_w  = (const float*)d_in[6];
  const float* bias   = (const float*)d_in[7];
  const float* gamma  = (const float*)d_in[8];
  const float* beta   = (const float*)d_in[9];

  char* ws = (char*)d_ws;
  unsigned short* Ab     = (unsigned short*)(ws + OFF_AB);
  unsigned short* Bb     = (unsigned short*)(ws + OFF_BB);
  unsigned short* hbuf   = (unsigned short*)(ws + OFF_H);
  unsigned short* resbuf = (unsigned short*)(ws + OFF_RES);
  float* elb    = (float*)(ws + OFF_EL);
  float* erb    = (float*)(ws + OFF_ER);
  int*   deg    = (int*)(ws + OFF_DEG);
  int*   rsb    = (int*)(ws + OFF_RS);
  int*   curb   = (int*)(ws + OFF_CUR);
  int*   esrc   = (int*)(ws + OFF_ESRC);
  int*   bsums  = (int*)(ws + OFF_BS);
  float* bnb    = (float*)(ws + OFF_BN);
  float* outp   = (float*)d_out;

  hipMemsetAsync(deg, 0, N_NODES * sizeof(int), stream);
  hipMemsetAsync(bnb, 0, 128 * sizeof(float), stream);

  k_pre<<<12539, 256, 0, stream>>>(feats, fc_w, res_w, dst, Ab, Bb, deg, hbuf, elb);
  k_mm<<<dim3(782, 2), 256, 0, stream>>>(Ab, Bb, bias, attn_l, attn_r,
                                         hbuf, resbuf, elb, erb);
  k_scan1<<<98, 256, 0, stream>>>(deg, rsb, bsums);
  k_scan3<<<391, 256, 0, stream>>>(rsb, bsums, curb, deg, esrc);
  k_scatter<<<6250, 256, 0, stream>>>(src, dst, curb, esrc);
  k_agg<<<2048, 256, 0, stream>>>(hbuf, resbuf, elb, erb, rsb, esrc, outp);
  k_bn_stats<<<256, 256, 0, stream>>>(outp, bnb);
  k_bn_apply<<<6250, 256, 0, stream>>>(outp, bnb, gamma, beta);
}

// Round 5
// 509.052 us; speedup vs baseline: 1.0350x; 1.0231x over previous
//
#include <hip/hip_runtime.h>

#define N_NODES 100000
#define N_EDGES 1600000
#define NEG_SLOPE 0.2f
#define BN_EPS 1e-5f

typedef __attribute__((ext_vector_type(8))) short short8;
typedef __attribute__((ext_vector_type(4))) float floatx4;
typedef __attribute__((ext_vector_type(8))) unsigned short u16x8;

// ---------------- workspace layout (bytes) ----------------
static const size_t OFF_AB   = 0;            // feats bf16 fragment-ordered [N_PAD,128]
static const size_t OFF_BB   = 25624576;     // weights bf16 fragment-ordered [512,128]
static const size_t OFF_H    = 25755648;     // h bf16 [N+1,256] (row N = sentinel zeros)
static const size_t OFF_RES  = 76956672;     // res+bias bf16 [N,256]
static const size_t OFF_EL   = 128156672;    // el [N+1,4] f32 (row N = -1e30 sentinel)
static const size_t OFF_ER   = 129757184;    // er [N,4] f32
static const size_t OFF_DEG  = 131357184;    // deg [N] i32
static const size_t OFF_RS   = 131757184;    // padded row_start [N+1] i32
static const size_t OFF_CUR  = 132157568;    // cursor [N] i32
static const size_t OFF_ESRC = 132557568;    // padded edge src ids [<=2.0M] i32
static const size_t OFF_BS   = 142157568;    // block sums [128] i32
static const size_t OFF_BN   = 142158080;    // bn accum [128] f32
// total ~142.2 MB

__device__ __forceinline__ unsigned short f2bf(float x) {
  unsigned int u = __float_as_uint(x);
  unsigned int r = (u + 0x7fffu + ((u >> 16) & 1u)) >> 16;   // RNE
  return (unsigned short)r;
}
__device__ __forceinline__ float bf2f(unsigned short u) {
  return __uint_as_float(((unsigned int)u) << 16);
}

// ---------------- fused pre-pass: cvt_a | edge count | cvt_w | sentinels ----
__global__ __launch_bounds__(256) void k_pre(
    const float* __restrict__ feats, const float* __restrict__ fc_w,
    const float* __restrict__ res_w, const int* __restrict__ dst,
    unsigned short* __restrict__ Ab, unsigned short* __restrict__ Bb,
    int* __restrict__ deg, unsigned short* __restrict__ hbuf,
    float* __restrict__ el)
{
  const int b = blockIdx.x;
  if (b < 6256) {                                // ---- cvt_a: N_PAD*16 chunks
    int c = b * 256 + threadIdx.x;
    int r = c >> 4, j = c & 15;
    unsigned short v[8];
    if (r < N_NODES) {
      const float* p = feats + (size_t)r * 128 + j * 8;
      float4 a = *(const float4*)p, bb = *(const float4*)(p + 4);
      v[0]=f2bf(a.x); v[1]=f2bf(a.y); v[2]=f2bf(a.z); v[3]=f2bf(a.w);
      v[4]=f2bf(bb.x); v[5]=f2bf(bb.y); v[6]=f2bf(bb.z); v[7]=f2bf(bb.w);
    } else {
      for (int i = 0; i < 8; i++) v[i] = 0;
    }
    size_t idx = (size_t)(r >> 7) * 2048 + ((r >> 4) & 7) * 256 + (j >> 2) * 64
               + (r & 15) + 16 * (j & 3);
    *(short8*)(Ab + idx * 8) = *(short8*)v;
  } else if (b < 12506) {                        // ---- count degrees
    int e = (b - 6256) * 256 + threadIdx.x;
    if (e < N_EDGES) atomicAdd(&deg[dst[e]], 1);
  } else if (b < 12538) {                        // ---- cvt_w: 8192 chunks
    int c = (b - 12506) * 256 + threadIdx.x;
    int n = c >> 4, j = c & 15;
    const float* W = (n < 256) ? (fc_w + (size_t)n * 128) : (res_w + (size_t)(n - 256) * 128);
    const float* p = W + j * 8;
    float4 a = *(const float4*)p, bb = *(const float4*)(p + 4);
    unsigned short v[8];
    v[0]=f2bf(a.x); v[1]=f2bf(a.y); v[2]=f2bf(a.z); v[3]=f2bf(a.w);
    v[4]=f2bf(bb.x); v[5]=f2bf(bb.y); v[6]=f2bf(bb.z); v[7]=f2bf(bb.w);
    size_t idx = (size_t)(n >> 7) * 2048 + ((n >> 4) & 7) * 256 + (j >> 2) * 64
               + (n & 15) + 16 * (j & 3);
    *(short8*)(Bb + idx * 8) = *(short8*)v;
  } else {                                       // ---- sentinel row init
    const int t = threadIdx.x;
    hbuf[(size_t)N_NODES * 256 + t] = 0;         // zero h row for dummy src
    if (t < 4) el[N_NODES * 4 + t] = -1e30f;     // weight-0 logit for dummy src
  }
}

// ---------------- CSR build (rows PADDED to multiples of 4) ----------------
__global__ __launch_bounds__(256) void k_scan1(const int* __restrict__ deg,
                                               int* __restrict__ rs, int* __restrict__ bsums)
{
  __shared__ int tmp[256];
  const int t = threadIdx.x;
  const int base = blockIdx.x * 1024 + t * 4;
  int v0 = 0, v1 = 0, v2 = 0, v3 = 0;
  if (base + 0 < N_NODES) v0 = (deg[base + 0] + 3) & ~3;
  if (base + 1 < N_NODES) v1 = (deg[base + 1] + 3) & ~3;
  if (base + 2 < N_NODES) v2 = (deg[base + 2] + 3) & ~3;
  if (base + 3 < N_NODES) v3 = (deg[base + 3] + 3) & ~3;
  const int tsum = v0 + v1 + v2 + v3;
  tmp[t] = tsum;
  __syncthreads();
  for (int o = 1; o < 256; o <<= 1) {
    int x = (t >= o) ? tmp[t - o] : 0;
    __syncthreads();
    tmp[t] += x;
    __syncthreads();
  }
  const int excl = tmp[t] - tsum;
  if (base + 0 < N_NODES) rs[base + 0] = excl;
  if (base + 1 < N_NODES) rs[base + 1] = excl + v0;
  if (base + 2 < N_NODES) rs[base + 2] = excl + v0 + v1;
  if (base + 3 < N_NODES) rs[base + 3] = excl + v0 + v1 + v2;
  if (t == 255) bsums[blockIdx.x] = tmp[t];
}

// finalize padded offsets + fill pad slots with sentinel src
__global__ __launch_bounds__(256) void k_scan3(int* __restrict__ rs,
                                               const int* __restrict__ bsums,
                                               int* __restrict__ cursor,
                                               const int* __restrict__ deg,
                                               int* __restrict__ esrc)
{
  __shared__ int sb[128];
  const int t = threadIdx.x;
  int raw = 0;
  if (t < 128) { raw = (t < 98) ? bsums[t] : 0; sb[t] = raw; }
  __syncthreads();
  for (int o = 1; o < 128; o <<= 1) {
    int x = (t >= o && t < 128) ? sb[t - o] : 0;
    __syncthreads();
    if (t < 128) sb[t] += x;
    __syncthreads();
  }
  if (t < 128) sb[t] -= raw;   // exclusive
  __syncthreads();
  const int i = blockIdx.x * 256 + t;
  if (i < N_NODES) {
    int v = rs[i] + sb[i >> 10];
    rs[i] = v;
    cursor[i] = v;
    const int d = deg[i];
    const int pd = (d + 3) & ~3;
    for (int j = d; j < pd; j++) esrc[v + j] = N_NODES;   // weight-0 dummies
    if (i == N_NODES - 1) rs[N_NODES] = v + pd;
  }
}

// ---------------- FUSED: MFMA projection ∥ edge scatter ---------------------
// mm (latency: MFMA/LDS-bound) and scatter (atomic-latency-bound) have no
// data dependence; interleave 4 scatter blocks : 1 mm block so every CU runs
// a blend and the atomic round-trips hide under MFMA work.
__global__ __launch_bounds__(256) void k_mmsc(
    const unsigned short* __restrict__ Ab, const unsigned short* __restrict__ Bb,
    const float* __restrict__ bias, const float* __restrict__ attn_l,
    const float* __restrict__ attn_r,
    unsigned short* __restrict__ hbuf, unsigned short* __restrict__ resbuf,
    float* __restrict__ el, float* __restrict__ er,
    const int* __restrict__ src, const int* __restrict__ dst,
    int* __restrict__ cursor, int* __restrict__ esrc)
{
  __shared__ unsigned short sA[16384];  // 32 KB (mm blocks only)
  const int b = blockIdx.x;
  const int g = b / 5, rrole = b % 5;

  if (rrole != 4) {                     // ---------------- scatter role
    const int e = (g * 4 + rrole) * 256 + threadIdx.x;
    if (e < N_EDGES) {
      int d = dst[e];
      int pos = atomicAdd(&cursor[d], 1);
      esrc[pos] = src[e];
    }
    return;
  }

  // ---------------- mm role: g in [0,1564) -> blk 0..781, nb 0..1
  const int tid = threadIdx.x;
  const int w = tid >> 6, L = tid & 63;
  const int blk = g >> 1, nbb = g & 1;

  {  // stage A: contiguous 32 KB, global_load_lds width 16
    const unsigned short* ga = Ab + (size_t)blk * 16384;
    #pragma unroll
    for (int i = 0; i < 8; i++) {
      int off = (i * 256 + w * 64) * 8;
      __builtin_amdgcn_global_load_lds(
          (const __attribute__((address_space(1))) unsigned int*)(ga + off + L * 8),
          (__attribute__((address_space(3))) unsigned int*)(sA + off),
          16, 0, 0);
    }
  }
  const int mh = w & 1, nh = w >> 1;
  __syncthreads();

  for (int wb = 0; wb < 2; ++wb) {
    const int nb = nbb + wb * 2;
    floatx4 acc[4][4] = {};
    const unsigned short* gb = Bb + ((size_t)nb * 2048 + nh * 4 * 256) * 8 + L * 8;
    #pragma unroll
    for (int s = 0; s < 4; s++) {
      short8 a[4], bfr[4];
      #pragma unroll
      for (int t = 0; t < 4; t++)
        a[t] = *(const short8*)(sA + ((mh * 4 + t) * 256 + s * 64 + L) * 8);
      #pragma unroll
      for (int t = 0; t < 4; t++)
        bfr[t] = *(const short8*)(gb + ((size_t)t * 256 + s * 64) * 8);
      #pragma unroll
      for (int mt = 0; mt < 4; mt++)
        #pragma unroll
        for (int nt = 0; nt < 4; nt++)
          acc[mt][nt] = __builtin_amdgcn_mfma_f32_16x16x32_bf16(a[mt], bfr[nt], acc[mt][nt], 0, 0, 0);
    }

    const int q = L >> 4, cn = L & 15;
    const int r0 = blk * 128 + mh * 64;
    if (nb < 2) {
      const int head = nb * 2 + nh;            // this wave owns one full head
      const int col0 = nb * 128 + nh * 64;
      float al[4], ar[4];
      #pragma unroll
      for (int nt = 0; nt < 4; nt++) {
        al[nt] = attn_l[head * 64 + nt * 16 + cn];
        ar[nt] = attn_r[head * 64 + nt * 16 + cn];
      }
      #pragma unroll
      for (int mt = 0; mt < 4; mt++)
        #pragma unroll
        for (int r = 0; r < 4; r++) {
          const int row = r0 + mt * 16 + q * 4 + r;
          float pl = 0.f, pr = 0.f;
          #pragma unroll
          for (int nt = 0; nt < 4; nt++) {
            pl = fmaf(acc[mt][nt][r], al[nt], pl);
            pr = fmaf(acc[mt][nt][r], ar[nt], pr);
          }
          #pragma unroll
          for (int o = 1; o < 16; o <<= 1) {
            pl += __shfl_xor(pl, o, 64);
            pr += __shfl_xor(pr, o, 64);
          }
          if (row < N_NODES) {
            #pragma unroll
            for (int nt = 0; nt < 4; nt++)
              hbuf[(size_t)row * 256 + col0 + nt * 16 + cn] = f2bf(acc[mt][nt][r]);
            if (cn == 0) {
              el[row * 4 + head] = pl;
              er[row * 4 + head] = pr;
            }
          }
        }
    } else {
      const int rc0 = (nb - 2) * 128 + nh * 64;
      #pragma unroll
      for (int mt = 0; mt < 4; mt++)
        #pragma unroll
        for (int r = 0; r < 4; r++) {
          const int row = r0 + mt * 16 + q * 4 + r;
          if (row < N_NODES)
            #pragma unroll
            for (int nt = 0; nt < 4; nt++) {
              float v = acc[mt][nt][r] + bias[rc0 + nt * 16 + cn];
              resbuf[(size_t)row * 256 + rc0 + nt * 16 + cn] = f2bf(v);
            }
        }
    }
  }
}

// ---------------- fused softmax + aggregation + residual/ELU/head-mean ------
// 2x32 split, depth-8 named-register rotation. Round-4 showed the scheduler
// COLLAPSES the source-level pipeline (VGPR 44 << state size): sched_barrier(0)
// after each step's load-issue group pins gather issue 6 batches ahead.
#define RFL(x) __builtin_amdgcn_readfirstlane(x)

#define GATHER(X) do { \
  const int s_ = (lane & 32) ? sn##X.y : sn##X.x; \
  hv##X = *(const u16x8*)(hbuf + (size_t)s_ * 256 + li8); \
  ev##X = el[s_ * 4 + head]; \
} while (0)

#define PRO(X, B) do { \
  if ((B) < p_end) { sn##X = *(const int2*)(esrc + (B)); GATHER(X); } \
} while (0)

#define COMPUTE(X) do { \
  float e_ = ev##X + ern; \
  e_ = fmaxf(e_, NEG_SLOPE * e_); \
  const float w_ = __expf(e_); \
  ssum += w_; \
  accA.x = fmaf(w_, bf2f(hv##X[0]), accA.x); \
  accA.y = fmaf(w_, bf2f(hv##X[1]), accA.y); \
  accA.z = fmaf(w_, bf2f(hv##X[2]), accA.z); \
  accA.w = fmaf(w_, bf2f(hv##X[3]), accA.w); \
  accB.x = fmaf(w_, bf2f(hv##X[4]), accB.x); \
  accB.y = fmaf(w_, bf2f(hv##X[5]), accB.y); \
  accB.z = fmaf(w_, bf2f(hv##X[6]), accB.z); \
  accB.w = fmaf(w_, bf2f(hv##X[7]), accB.w); \
} while (0)

#define FIN(ND) do { \
  float st_ = ssum + __shfl_xor(ssum, 32, 64); \
  float a0_ = accA.x + __shfl_xor(accA.x, 32, 64); \
  float a1_ = accA.y + __shfl_xor(accA.y, 32, 64); \
  float a2_ = accA.z + __shfl_xor(accA.z, 32, 64); \
  float a3_ = accA.w + __shfl_xor(accA.w, 32, 64); \
  float a4_ = accB.x + __shfl_xor(accB.x, 32, 64); \
  float a5_ = accB.y + __shfl_xor(accB.y, 32, 64); \
  float a6_ = accB.z + __shfl_xor(accB.z, 32, 64); \
  float a7_ = accB.w + __shfl_xor(accB.w, 32, 64); \
  const float inv_ = (st_ > 0.f) ? (1.0f / st_) : 0.f; \
  a0_ = fmaf(a0_, inv_, bf2f(rv_cur[0])); \
  a1_ = fmaf(a1_, inv_, bf2f(rv_cur[1])); \
  a2_ = fmaf(a2_, inv_, bf2f(rv_cur[2])); \
  a3_ = fmaf(a3_, inv_, bf2f(rv_cur[3])); \
  a4_ = fmaf(a4_, inv_, bf2f(rv_cur[4])); \
  a5_ = fmaf(a5_, inv_, bf2f(rv_cur[5])); \
  a6_ = fmaf(a6_, inv_, bf2f(rv_cur[6])); \
  a7_ = fmaf(a7_, inv_, bf2f(rv_cur[7])); \
  a0_ = (a0_ > 0.f) ? a0_ : (__expf(a0_) - 1.f); \
  a1_ = (a1_ > 0.f) ? a1_ : (__expf(a1_) - 1.f); \
  a2_ = (a2_ > 0.f) ? a2_ : (__expf(a2_) - 1.f); \
  a3_ = (a3_ > 0.f) ? a3_ : (__expf(a3_) - 1.f); \
  a4_ = (a4_ > 0.f) ? a4_ : (__expf(a4_) - 1.f); \
  a5_ = (a5_ > 0.f) ? a5_ : (__expf(a5_) - 1.f); \
  a6_ = (a6_ > 0.f) ? a6_ : (__expf(a6_) - 1.f); \
  a7_ = (a7_ > 0.f) ? a7_ : (__expf(a7_) - 1.f); \
  a0_ += __shfl_xor(a0_, 8, 64);  a0_ += __shfl_xor(a0_, 16, 64); \
  a1_ += __shfl_xor(a1_, 8, 64);  a1_ += __shfl_xor(a1_, 16, 64); \
  a2_ += __shfl_xor(a2_, 8, 64);  a2_ += __shfl_xor(a2_, 16, 64); \
  a3_ += __shfl_xor(a3_, 8, 64);  a3_ += __shfl_xor(a3_, 16, 64); \
  a4_ += __shfl_xor(a4_, 8, 64);  a4_ += __shfl_xor(a4_, 16, 64); \
  a5_ += __shfl_xor(a5_, 8, 64);  a5_ += __shfl_xor(a5_, 16, 64); \
  a6_ += __shfl_xor(a6_, 8, 64);  a6_ += __shfl_xor(a6_, 16, 64); \
  a7_ += __shfl_xor(a7_, 8, 64);  a7_ += __shfl_xor(a7_, 16, 64); \
  if (lane < 8) { \
    float4 o1_, o2_; \
    o1_.x = a0_ * 0.25f; o1_.y = a1_ * 0.25f; o1_.z = a2_ * 0.25f; o1_.w = a3_ * 0.25f; \
    o2_.x = a4_ * 0.25f; o2_.y = a5_ * 0.25f; o2_.z = a6_ * 0.25f; o2_.w = a7_ * 0.25f; \
    *(float4*)(out + (size_t)(ND) * 64 + li8) = o1_; \
    *(float4*)(out + (size_t)(ND) * 64 + li8 + 4) = o2_; \
  } \
} while (0)

#define BOUNDARY() \
  while (p == nend) { \
    FIN(nu); \
    accA.x=0.f; accA.y=0.f; accA.z=0.f; accA.w=0.f; \
    accB.x=0.f; accB.y=0.f; accB.z=0.f; accB.w=0.f; ssum = 0.f; \
    nu++; \
    nend = nendN; ern = ernN; rv_cur = rvN; \
    const int f1_ = (nu + 1 < N_NODES) ? (nu + 1) : (N_NODES - 1); \
    const int f2_ = (nu + 2 <= N_NODES) ? (nu + 2) : N_NODES; \
    nendN = RFL(rs[f2_]); \
    ernN = er[f1_ * 4 + head]; \
    rvN = *(const u16x8*)(resbuf + (size_t)f1_ * 256 + li8); \
  }

// STEP(CUR, GAT): compute batch p (slot CUR), gather batch p+12 (slot GAT),
// load src ids for batch p+16 (slot CUR). sched_barrier(0) pins the load
// issue BEFORE boundary/compute so the scheduler cannot sink it.
#define STEP(CUR, GAT) do { \
  if (p + 12 < p_end) GATHER(GAT); \
  if (p + 16 < p_end) sn##CUR = *(const int2*)(esrc + p + 16); \
  __builtin_amdgcn_sched_barrier(0); \
  BOUNDARY(); \
  COMPUTE(CUR); \
} while (0)

__global__ __launch_bounds__(256, 4) void k_agg(
    const unsigned short* __restrict__ hbuf, const unsigned short* __restrict__ resbuf,
    const float* __restrict__ el, const float* __restrict__ er,
    const int* __restrict__ rs, const int* __restrict__ esrc,
    float* __restrict__ out)
{
  const int lane = threadIdx.x & 63;
  const int li = lane & 31;
  const int head = li >> 3;          // 4 heads x 8 lanes per 32-half
  const int li8 = li * 8;            // 8 dims per lane
  const int wid = blockIdx.x * 4 + (threadIdx.x >> 6);
  const int nW = gridDim.x * 4;

  const int n0 = (int)(((long long)wid * N_NODES) / nW);
  const int n1 = (int)(((long long)(wid + 1) * N_NODES) / nW);
  if (n0 >= n1) return;

  int nu = RFL(n0);
  const int p_end = RFL(rs[n1]);
  int nend = RFL(rs[nu + 1]);
  int f1 = (nu + 1 < N_NODES) ? (nu + 1) : (N_NODES - 1);
  int f2 = (nu + 2 <= N_NODES) ? (nu + 2) : N_NODES;
  int nendN = RFL(rs[f2]);
  float ern  = er[nu * 4 + head];
  float ernN = er[f1 * 4 + head];
  u16x8 rv_cur = *(const u16x8*)(resbuf + (size_t)nu * 256 + li8);
  u16x8 rvN    = *(const u16x8*)(resbuf + (size_t)f1 * 256 + li8);

  float4 accA = make_float4(0.f, 0.f, 0.f, 0.f);
  float4 accB = make_float4(0.f, 0.f, 0.f, 0.f);
  float ssum = 0.f;

  int2 snA, snB, snC, snD, snE, snF, snG, snH;
  float evA, evB, evC, evD, evE, evF, evG, evH;
  u16x8 hvA, hvB, hvC, hvD, hvE, hvF, hvG, hvH;

  int p = RFL(rs[nu]);               // multiple of 4 (slots are relative)
  PRO(A, p);      PRO(B, p + 2);  PRO(C, p + 4);  PRO(D, p + 6);
  PRO(E, p + 8);  PRO(F, p + 10);
  if (p + 12 < p_end) snG = *(const int2*)(esrc + p + 12);
  if (p + 14 < p_end) snH = *(const int2*)(esrc + p + 14);
  __builtin_amdgcn_sched_barrier(0);

  while (p < p_end) {
    STEP(A, G); p += 2; if (p >= p_end) break;
    STEP(B, H); p += 2; if (p >= p_end) break;
    STEP(C, A); p += 2; if (p >= p_end) break;
    STEP(D, B); p += 2; if (p >= p_end) break;
    STEP(E, C); p += 2; if (p >= p_end) break;
    STEP(F, D); p += 2; if (p >= p_end) break;
    STEP(G, E); p += 2; if (p >= p_end) break;
    STEP(H, F); p += 2;
  }

  // drain: finalize last node + trailing zero-degree nodes
  while (nu < n1) {
    FIN(nu);
    accA.x=0.f; accA.y=0.f; accA.z=0.f; accA.w=0.f;
    accB.x=0.f; accB.y=0.f; accB.z=0.f; accB.w=0.f; ssum = 0.f;
    nu++;
    if (nu < n1) rv_cur = *(const u16x8*)(resbuf + (size_t)nu * 256 + li8);
  }
}

// ---------------- BN stats over out (separate small pass) ----------------
__global__ __launch_bounds__(256) void k_bn_stats(const float* __restrict__ out,
                                                  float* __restrict__ bn)
{
  const int t = threadIdx.x;
  const int c4 = (t & 15) * 4;
  const int rg = t >> 4;
  float4 s = make_float4(0.f, 0.f, 0.f, 0.f);
  float4 q = make_float4(0.f, 0.f, 0.f, 0.f);
  for (int row = blockIdx.x * 16 + rg; row < N_NODES; row += gridDim.x * 16) {
    float4 v = *(const float4*)(out + (size_t)row * 64 + c4);
    s.x += v.x; s.y += v.y; s.z += v.z; s.w += v.w;
    q.x += v.x * v.x; q.y += v.y * v.y; q.z += v.z * v.z; q.w += v.w * v.w;
  }
  __shared__ float ls[64], lq[64];
  if (t < 64) { ls[t] = 0.f; lq[t] = 0.f; }
  __syncthreads();
  atomicAdd(&ls[c4 + 0], s.x); atomicAdd(&ls[c4 + 1], s.y);
  atomicAdd(&ls[c4 + 2], s.z); atomicAdd(&ls[c4 + 3], s.w);
  atomicAdd(&lq[c4 + 0], q.x); atomicAdd(&lq[c4 + 1], q.y);
  atomicAdd(&lq[c4 + 2], q.z); atomicAdd(&lq[c4 + 3], q.w);
  __syncthreads();
  if (t < 64) {
    atomicAdd(&bn[t], ls[t]);
    atomicAdd(&bn[64 + t], lq[t]);
  }
}

// ---------------- batchnorm apply ----------------
__global__ __launch_bounds__(256) void k_bn_apply(float* __restrict__ out,
                                                  const float* __restrict__ bn,
                                                  const float* __restrict__ gamma,
                                                  const float* __restrict__ beta)
{
  __shared__ float sc[64], sh[64];
  const int t = threadIdx.x;
  if (t < 64) {
    float mean = bn[t] * (1.0f / N_NODES);
    float var = bn[64 + t] * (1.0f / N_NODES) - mean * mean;
    float s = gamma[t] * rsqrtf(var + BN_EPS);
    sc[t] = s;
    sh[t] = beta[t] - mean * s;
  }
  __syncthreads();
  const int i = blockIdx.x * 256 + t;
  if (i >= N_NODES * 16) return;
  const int d0 = (i & 15) * 4;
  float4 v = *(float4*)(out + (size_t)i * 4);
  v.x = fmaf(v.x, sc[d0 + 0], sh[d0 + 0]);
  v.y = fmaf(v.y, sc[d0 + 1], sh[d0 + 1]);
  v.z = fmaf(v.z, sc[d0 + 2], sh[d0 + 2]);
  v.w = fmaf(v.w, sc[d0 + 3], sh[d0 + 3]);
  *(float4*)(out + (size_t)i * 4) = v;
}

extern "C" void kernel_launch(void* const* d_in, const int* in_sizes, int n_in,
                              void* d_out, int out_size, void* d_ws, size_t ws_size,
                              hipStream_t stream)
{
  const float* feats  = (const float*)d_in[0];
  const int*   src    = (const int*)d_in[1];
  const int*   dst    = (const int*)d_in[2];
  const float* fc_w   = (const float*)d_in[3];
  const float* attn_l = (const float*)d_in[4];
  const float* attn_r = (const float*)d_in[5];
  const float* res_w  = (const float*)d_in[6];
  const float* bias   = (const float*)d_in[7];
  const float* gamma  = (const float*)d_in[8];
  const float* beta   = (const float*)d_in[9];

  char* ws = (char*)d_ws;
  unsigned short* Ab     = (unsigned short*)(ws + OFF_AB);
  unsigned short* Bb     = (unsigned short*)(ws + OFF_BB);
  unsigned short* hbuf   = (unsigned short*)(ws + OFF_H);
  unsigned short* resbuf = (unsigned short*)(ws + OFF_RES);
  float* elb    = (float*)(ws + OFF_EL);
  float* erb    = (float*)(ws + OFF_ER);
  int*   deg    = (int*)(ws + OFF_DEG);
  int*   rsb    = (int*)(ws + OFF_RS);
  int*   curb   = (int*)(ws + OFF_CUR);
  int*   esrc   = (int*)(ws + OFF_ESRC);
  int*   bsums  = (int*)(ws + OFF_BS);
  float* bnb    = (float*)(ws + OFF_BN);
  float* outp   = (float*)d_out;

  hipMemsetAsync(deg, 0, N_NODES * sizeof(int), stream);
  hipMemsetAsync(bnb, 0, 128 * sizeof(float), stream);

  k_pre<<<12539, 256, 0, stream>>>(feats, fc_w, res_w, dst, Ab, Bb, deg, hbuf, elb);
  k_scan1<<<98, 256, 0, stream>>>(deg, rsb, bsums);
  k_scan3<<<391, 256, 0, stream>>>(rsb, bsums, curb, deg, esrc);
  k_mmsc<<<7820, 256, 0, stream>>>(Ab, Bb, bias, attn_l, attn_r,
                                   hbuf, resbuf, elb, erb,
                                   src, dst, curb, esrc);
  k_agg<<<2048, 256, 0, stream>>>(hbuf, resbuf, elb, erb, rsb, esrc, outp);
  k_bn_stats<<<256, 256, 0, stream>>>(outp, bnb);
  k_bn_apply<<<6250, 256, 0, stream>>>(outp, bnb, gamma, beta);
}

// Round 6
// 454.580 us; speedup vs baseline: 1.1591x; 1.1198x over previous
//
#include <hip/hip_runtime.h>

#define N_NODES 100000
#define N_EDGES 1600000
#define NEG_SLOPE 0.2f
#define BN_EPS 1e-5f

typedef __attribute__((ext_vector_type(8))) short short8;
typedef __attribute__((ext_vector_type(4))) float floatx4;
typedef __attribute__((ext_vector_type(8))) unsigned short u16x8;

// ---------------- workspace layout (bytes) ----------------
static const size_t OFF_AB   = 0;            // feats bf16 fragment-ordered [N_PAD,128]
static const size_t OFF_BB   = 25624576;     // weights bf16 fragment-ordered [512,128]
static const size_t OFF_H    = 25755648;     // h bf16 [N+1,256] (row N = sentinel zeros)
static const size_t OFF_RES  = 76956672;     // res+bias bf16 [N,256]
static const size_t OFF_EL   = 128156672;    // el [N+1,4] f32 (row N = -1e30 sentinel)
static const size_t OFF_ER   = 129757184;    // er [N,4] f32
static const size_t OFF_DEG  = 131357184;    // deg [N] i32
static const size_t OFF_RS   = 131757184;    // padded row_start [N+1] i32
static const size_t OFF_BNP  = 132157568;    // bn accum, LINE-PADDED: 128 slots x stride 16 f32 (8 KB)
static const size_t OFF_ESRC = 132557568;    // padded edge src ids [<=2.0M] i32
static const size_t OFF_BS   = 142157568;    // block sums [128] i32
// rank[e] scratch lives in d_out (first 6.4 MB; overwritten later by k_agg)

__device__ __forceinline__ unsigned short f2bf(float x) {
  unsigned int u = __float_as_uint(x);
  unsigned int r = (u + 0x7fffu + ((u >> 16) & 1u)) >> 16;   // RNE
  return (unsigned short)r;
}
__device__ __forceinline__ float bf2f(unsigned short u) {
  return __uint_as_float(((unsigned int)u) << 16);
}

// ---------------- fused pre-pass: cvt_a | count+rank | cvt_w | sentinels ----
// count role: atomicAdd's RETURN is the within-row rank -> stored so the
// placement pass needs no atomics (halves the CSR build's atomic passes).
__global__ __launch_bounds__(256) void k_pre(
    const float* __restrict__ feats, const float* __restrict__ fc_w,
    const float* __restrict__ res_w, const int* __restrict__ dst,
    unsigned short* __restrict__ Ab, unsigned short* __restrict__ Bb,
    int* __restrict__ deg, unsigned short* __restrict__ hbuf,
    float* __restrict__ el, int* __restrict__ rank)
{
  const int b = blockIdx.x;
  if (b < 6256) {                                // ---- cvt_a: N_PAD*16 chunks
    int c = b * 256 + threadIdx.x;
    int r = c >> 4, j = c & 15;
    unsigned short v[8];
    if (r < N_NODES) {
      const float* p = feats + (size_t)r * 128 + j * 8;
      float4 a = *(const float4*)p, bb = *(const float4*)(p + 4);
      v[0]=f2bf(a.x); v[1]=f2bf(a.y); v[2]=f2bf(a.z); v[3]=f2bf(a.w);
      v[4]=f2bf(bb.x); v[5]=f2bf(bb.y); v[6]=f2bf(bb.z); v[7]=f2bf(bb.w);
    } else {
      for (int i = 0; i < 8; i++) v[i] = 0;
    }
    size_t idx = (size_t)(r >> 7) * 2048 + ((r >> 4) & 7) * 256 + (j >> 2) * 64
               + (r & 15) + 16 * (j & 3);
    *(short8*)(Ab + idx * 8) = *(short8*)v;
  } else if (b < 12506) {                        // ---- count degrees + rank
    int e = (b - 6256) * 256 + threadIdx.x;
    if (e < N_EDGES) rank[e] = atomicAdd(&deg[dst[e]], 1);
  } else if (b < 12538) {                        // ---- cvt_w: 8192 chunks
    int c = (b - 12506) * 256 + threadIdx.x;
    int n = c >> 4, j = c & 15;
    const float* W = (n < 256) ? (fc_w + (size_t)n * 128) : (res_w + (size_t)(n - 256) * 128);
    const float* p = W + j * 8;
    float4 a = *(const float4*)p, bb = *(const float4*)(p + 4);
    unsigned short v[8];
    v[0]=f2bf(a.x); v[1]=f2bf(a.y); v[2]=f2bf(a.z); v[3]=f2bf(a.w);
    v[4]=f2bf(bb.x); v[5]=f2bf(bb.y); v[6]=f2bf(bb.z); v[7]=f2bf(bb.w);
    size_t idx = (size_t)(n >> 7) * 2048 + ((n >> 4) & 7) * 256 + (j >> 2) * 64
               + (n & 15) + 16 * (j & 3);
    *(short8*)(Bb + idx * 8) = *(short8*)v;
  } else {                                       // ---- sentinel row init
    const int t = threadIdx.x;
    hbuf[(size_t)N_NODES * 256 + t] = 0;         // zero h row for dummy src
    if (t < 4) el[N_NODES * 4 + t] = -1e30f;     // weight-0 logit for dummy src
  }
}

// ---------------- CSR build (rows PADDED to multiples of 4) ----------------
__global__ __launch_bounds__(256) void k_scan1(const int* __restrict__ deg,
                                               int* __restrict__ rs, int* __restrict__ bsums)
{
  __shared__ int tmp[256];
  const int t = threadIdx.x;
  const int base = blockIdx.x * 1024 + t * 4;
  int v0 = 0, v1 = 0, v2 = 0, v3 = 0;
  if (base + 0 < N_NODES) v0 = (deg[base + 0] + 3) & ~3;
  if (base + 1 < N_NODES) v1 = (deg[base + 1] + 3) & ~3;
  if (base + 2 < N_NODES) v2 = (deg[base + 2] + 3) & ~3;
  if (base + 3 < N_NODES) v3 = (deg[base + 3] + 3) & ~3;
  const int tsum = v0 + v1 + v2 + v3;
  tmp[t] = tsum;
  __syncthreads();
  for (int o = 1; o < 256; o <<= 1) {
    int x = (t >= o) ? tmp[t - o] : 0;
    __syncthreads();
    tmp[t] += x;
    __syncthreads();
  }
  const int excl = tmp[t] - tsum;
  if (base + 0 < N_NODES) rs[base + 0] = excl;
  if (base + 1 < N_NODES) rs[base + 1] = excl + v0;
  if (base + 2 < N_NODES) rs[base + 2] = excl + v0 + v1;
  if (base + 3 < N_NODES) rs[base + 3] = excl + v0 + v1 + v2;
  if (t == 255) bsums[blockIdx.x] = tmp[t];
}

// finalize padded offsets + fill pad slots with sentinel src
__global__ __launch_bounds__(256) void k_scan3(int* __restrict__ rs,
                                               const int* __restrict__ bsums,
                                               const int* __restrict__ deg,
                                               int* __restrict__ esrc)
{
  __shared__ int sb[128];
  const int t = threadIdx.x;
  int raw = 0;
  if (t < 128) { raw = (t < 98) ? bsums[t] : 0; sb[t] = raw; }
  __syncthreads();
  for (int o = 1; o < 128; o <<= 1) {
    int x = (t >= o && t < 128) ? sb[t - o] : 0;
    __syncthreads();
    if (t < 128) sb[t] += x;
    __syncthreads();
  }
  if (t < 128) sb[t] -= raw;   // exclusive
  __syncthreads();
  const int i = blockIdx.x * 256 + t;
  if (i < N_NODES) {
    int v = rs[i] + sb[i >> 10];
    rs[i] = v;
    const int d = deg[i];
    const int pd = (d + 3) & ~3;
    for (int j = d; j < pd; j++) esrc[v + j] = N_NODES;   // weight-0 dummies
    if (i == N_NODES - 1) rs[N_NODES] = v + pd;
  }
}

// ---------------- atomic-free edge placement ----------------
// pos = row_start[dst] + rank (rank captured by the count-phase atomic).
__global__ __launch_bounds__(256) void k_place(const int* __restrict__ src,
                                               const int* __restrict__ dst,
                                               const int* __restrict__ rs,
                                               const int* __restrict__ rank,
                                               int* __restrict__ esrc)
{
  int e = blockIdx.x * 256 + threadIdx.x;
  if (e >= N_EDGES) return;
  esrc[rs[dst[e]] + rank[e]] = src[e];
}

// ---------------- MFMA projection + fused el/er -----------------------------
// grid (782, 2): block stages A once, inner loop computes h-half and res-half.
__global__ __launch_bounds__(256) void k_mm(
    const unsigned short* __restrict__ Ab, const unsigned short* __restrict__ Bb,
    const float* __restrict__ bias, const float* __restrict__ attn_l,
    const float* __restrict__ attn_r,
    unsigned short* __restrict__ hbuf, unsigned short* __restrict__ resbuf,
    float* __restrict__ el, float* __restrict__ er)
{
  __shared__ unsigned short sA[16384];  // 32 KB, fragment-ordered A block
  const int tid = threadIdx.x;
  const int w = tid >> 6, L = tid & 63;
  const int blk = blockIdx.x;

  {  // stage A: contiguous 32 KB, global_load_lds width 16
    const unsigned short* ga = Ab + (size_t)blk * 16384;
    #pragma unroll
    for (int i = 0; i < 8; i++) {
      int off = (i * 256 + w * 64) * 8;
      __builtin_amdgcn_global_load_lds(
          (const __attribute__((address_space(1))) unsigned int*)(ga + off + L * 8),
          (__attribute__((address_space(3))) unsigned int*)(sA + off),
          16, 0, 0);
    }
  }
  const int mh = w & 1, nh = w >> 1;
  __syncthreads();

  for (int wb = 0; wb < 2; ++wb) {
    const int nb = blockIdx.y + wb * 2;
    floatx4 acc[4][4] = {};
    const unsigned short* gb = Bb + ((size_t)nb * 2048 + nh * 4 * 256) * 8 + L * 8;
    #pragma unroll
    for (int s = 0; s < 4; s++) {
      short8 a[4], b[4];
      #pragma unroll
      for (int t = 0; t < 4; t++)
        a[t] = *(const short8*)(sA + ((mh * 4 + t) * 256 + s * 64 + L) * 8);
      #pragma unroll
      for (int t = 0; t < 4; t++)
        b[t] = *(const short8*)(gb + ((size_t)t * 256 + s * 64) * 8);
      #pragma unroll
      for (int mt = 0; mt < 4; mt++)
        #pragma unroll
        for (int nt = 0; nt < 4; nt++)
          acc[mt][nt] = __builtin_amdgcn_mfma_f32_16x16x32_bf16(a[mt], b[nt], acc[mt][nt], 0, 0, 0);
    }

    const int q = L >> 4, cn = L & 15;
    const int r0 = blk * 128 + mh * 64;
    if (nb < 2) {
      const int head = nb * 2 + nh;            // this wave owns one full head
      const int col0 = nb * 128 + nh * 64;
      float al[4], ar[4];
      #pragma unroll
      for (int nt = 0; nt < 4; nt++) {
        al[nt] = attn_l[head * 64 + nt * 16 + cn];
        ar[nt] = attn_r[head * 64 + nt * 16 + cn];
      }
      #pragma unroll
      for (int mt = 0; mt < 4; mt++)
        #pragma unroll
        for (int r = 0; r < 4; r++) {
          const int row = r0 + mt * 16 + q * 4 + r;
          float pl = 0.f, pr = 0.f;
          #pragma unroll
          for (int nt = 0; nt < 4; nt++) {
            pl = fmaf(acc[mt][nt][r], al[nt], pl);
            pr = fmaf(acc[mt][nt][r], ar[nt], pr);
          }
          #pragma unroll
          for (int o = 1; o < 16; o <<= 1) {
            pl += __shfl_xor(pl, o, 64);
            pr += __shfl_xor(pr, o, 64);
          }
          if (row < N_NODES) {
            #pragma unroll
            for (int nt = 0; nt < 4; nt++)
              hbuf[(size_t)row * 256 + col0 + nt * 16 + cn] = f2bf(acc[mt][nt][r]);
            if (cn == 0) {
              el[row * 4 + head] = pl;
              er[row * 4 + head] = pr;
            }
          }
        }
    } else {
      const int rc0 = (nb - 2) * 128 + nh * 64;
      #pragma unroll
      for (int mt = 0; mt < 4; mt++)
        #pragma unroll
        for (int r = 0; r < 4; r++) {
          const int row = r0 + mt * 16 + q * 4 + r;
          if (row < N_NODES)
            #pragma unroll
            for (int nt = 0; nt < 4; nt++) {
              float v = acc[mt][nt][r] + bias[rc0 + nt * 16 + cn];
              resbuf[(size_t)row * 256 + rc0 + nt * 16 + cn] = f2bf(v);
            }
        }
    }
  }
}

// ---------------- fused softmax + aggregation + res/ELU/mean + BN stats -----
// 2x32 split, depth-8 named-register rotation, sched_barrier-pinned pipeline.
// BN sum/sumsq folded in via LDS atomics (zero VGPR cost), flushed to a
// LINE-PADDED global accumulator (stride 16 f32 -> 128 distinct lines).
#define RFL(x) __builtin_amdgcn_readfirstlane(x)

#define GATHER(X) do { \
  const int s_ = (lane & 32) ? sn##X.y : sn##X.x; \
  hv##X = *(const u16x8*)(hbuf + (size_t)s_ * 256 + li8); \
  ev##X = el[s_ * 4 + head]; \
} while (0)

#define PRO(X, B) do { \
  if ((B) < p_end) { sn##X = *(const int2*)(esrc + (B)); GATHER(X); } \
} while (0)

#define COMPUTE(X) do { \
  float e_ = ev##X + ern; \
  e_ = fmaxf(e_, NEG_SLOPE * e_); \
  const float w_ = __expf(e_); \
  ssum += w_; \
  accA.x = fmaf(w_, bf2f(hv##X[0]), accA.x); \
  accA.y = fmaf(w_, bf2f(hv##X[1]), accA.y); \
  accA.z = fmaf(w_, bf2f(hv##X[2]), accA.z); \
  accA.w = fmaf(w_, bf2f(hv##X[3]), accA.w); \
  accB.x = fmaf(w_, bf2f(hv##X[4]), accB.x); \
  accB.y = fmaf(w_, bf2f(hv##X[5]), accB.y); \
  accB.z = fmaf(w_, bf2f(hv##X[6]), accB.z); \
  accB.w = fmaf(w_, bf2f(hv##X[7]), accB.w); \
} while (0)

#define FIN(ND) do { \
  float st_ = ssum + __shfl_xor(ssum, 32, 64); \
  float a0_ = accA.x + __shfl_xor(accA.x, 32, 64); \
  float a1_ = accA.y + __shfl_xor(accA.y, 32, 64); \
  float a2_ = accA.z + __shfl_xor(accA.z, 32, 64); \
  float a3_ = accA.w + __shfl_xor(accA.w, 32, 64); \
  float a4_ = accB.x + __shfl_xor(accB.x, 32, 64); \
  float a5_ = accB.y + __shfl_xor(accB.y, 32, 64); \
  float a6_ = accB.z + __shfl_xor(accB.z, 32, 64); \
  float a7_ = accB.w + __shfl_xor(accB.w, 32, 64); \
  const float inv_ = (st_ > 0.f) ? (1.0f / st_) : 0.f; \
  a0_ = fmaf(a0_, inv_, bf2f(rv_cur[0])); \
  a1_ = fmaf(a1_, inv_, bf2f(rv_cur[1])); \
  a2_ = fmaf(a2_, inv_, bf2f(rv_cur[2])); \
  a3_ = fmaf(a3_, inv_, bf2f(rv_cur[3])); \
  a4_ = fmaf(a4_, inv_, bf2f(rv_cur[4])); \
  a5_ = fmaf(a5_, inv_, bf2f(rv_cur[5])); \
  a6_ = fmaf(a6_, inv_, bf2f(rv_cur[6])); \
  a7_ = fmaf(a7_, inv_, bf2f(rv_cur[7])); \
  a0_ = (a0_ > 0.f) ? a0_ : (__expf(a0_) - 1.f); \
  a1_ = (a1_ > 0.f) ? a1_ : (__expf(a1_) - 1.f); \
  a2_ = (a2_ > 0.f) ? a2_ : (__expf(a2_) - 1.f); \
  a3_ = (a3_ > 0.f) ? a3_ : (__expf(a3_) - 1.f); \
  a4_ = (a4_ > 0.f) ? a4_ : (__expf(a4_) - 1.f); \
  a5_ = (a5_ > 0.f) ? a5_ : (__expf(a5_) - 1.f); \
  a6_ = (a6_ > 0.f) ? a6_ : (__expf(a6_) - 1.f); \
  a7_ = (a7_ > 0.f) ? a7_ : (__expf(a7_) - 1.f); \
  a0_ += __shfl_xor(a0_, 8, 64);  a0_ += __shfl_xor(a0_, 16, 64); \
  a1_ += __shfl_xor(a1_, 8, 64);  a1_ += __shfl_xor(a1_, 16, 64); \
  a2_ += __shfl_xor(a2_, 8, 64);  a2_ += __shfl_xor(a2_, 16, 64); \
  a3_ += __shfl_xor(a3_, 8, 64);  a3_ += __shfl_xor(a3_, 16, 64); \
  a4_ += __shfl_xor(a4_, 8, 64);  a4_ += __shfl_xor(a4_, 16, 64); \
  a5_ += __shfl_xor(a5_, 8, 64);  a5_ += __shfl_xor(a5_, 16, 64); \
  a6_ += __shfl_xor(a6_, 8, 64);  a6_ += __shfl_xor(a6_, 16, 64); \
  a7_ += __shfl_xor(a7_, 8, 64);  a7_ += __shfl_xor(a7_, 16, 64); \
  if (lane < 8) { \
    float4 o1_, o2_; \
    o1_.x = a0_ * 0.25f; o1_.y = a1_ * 0.25f; o1_.z = a2_ * 0.25f; o1_.w = a3_ * 0.25f; \
    o2_.x = a4_ * 0.25f; o2_.y = a5_ * 0.25f; o2_.z = a6_ * 0.25f; o2_.w = a7_ * 0.25f; \
    *(float4*)(out + (size_t)(ND) * 64 + li8) = o1_; \
    *(float4*)(out + (size_t)(ND) * 64 + li8 + 4) = o2_; \
    atomicAdd(&ls[li8 + 0], o1_.x); atomicAdd(&ls[li8 + 1], o1_.y); \
    atomicAdd(&ls[li8 + 2], o1_.z); atomicAdd(&ls[li8 + 3], o1_.w); \
    atomicAdd(&ls[li8 + 4], o2_.x); atomicAdd(&ls[li8 + 5], o2_.y); \
    atomicAdd(&ls[li8 + 6], o2_.z); atomicAdd(&ls[li8 + 7], o2_.w); \
    atomicAdd(&lq[li8 + 0], o1_.x * o1_.x); atomicAdd(&lq[li8 + 1], o1_.y * o1_.y); \
    atomicAdd(&lq[li8 + 2], o1_.z * o1_.z); atomicAdd(&lq[li8 + 3], o1_.w * o1_.w); \
    atomicAdd(&lq[li8 + 4], o2_.x * o2_.x); atomicAdd(&lq[li8 + 5], o2_.y * o2_.y); \
    atomicAdd(&lq[li8 + 6], o2_.z * o2_.z); atomicAdd(&lq[li8 + 7], o2_.w * o2_.w); \
  } \
} while (0)

#define BOUNDARY() \
  while (p == nend) { \
    FIN(nu); \
    accA.x=0.f; accA.y=0.f; accA.z=0.f; accA.w=0.f; \
    accB.x=0.f; accB.y=0.f; accB.z=0.f; accB.w=0.f; ssum = 0.f; \
    nu++; \
    nend = nendN; ern = ernN; rv_cur = rvN; \
    const int f1_ = (nu + 1 < N_NODES) ? (nu + 1) : (N_NODES - 1); \
    const int f2_ = (nu + 2 <= N_NODES) ? (nu + 2) : N_NODES; \
    nendN = RFL(rs[f2_]); \
    ernN = er[f1_ * 4 + head]; \
    rvN = *(const u16x8*)(resbuf + (size_t)f1_ * 256 + li8); \
  }

#define STEP(CUR, GAT) do { \
  if (p + 12 < p_end) GATHER(GAT); \
  if (p + 16 < p_end) sn##CUR = *(const int2*)(esrc + p + 16); \
  __builtin_amdgcn_sched_barrier(0); \
  BOUNDARY(); \
  COMPUTE(CUR); \
} while (0)

__global__ __launch_bounds__(256, 4) void k_agg(
    const unsigned short* __restrict__ hbuf, const unsigned short* __restrict__ resbuf,
    const float* __restrict__ el, const float* __restrict__ er,
    const int* __restrict__ rs, const int* __restrict__ esrc,
    float* __restrict__ out, float* __restrict__ bn)
{
  __shared__ float ls[64], lq[64];
  const int lane = threadIdx.x & 63;
  const int li = lane & 31;
  const int head = li >> 3;          // 4 heads x 8 lanes per 32-half
  const int li8 = li * 8;            // 8 dims per lane
  const int wid = blockIdx.x * 4 + (threadIdx.x >> 6);
  const int nW = gridDim.x * 4;

  if (threadIdx.x < 64) { ls[threadIdx.x] = 0.f; lq[threadIdx.x] = 0.f; }
  __syncthreads();

  const int n0 = (int)(((long long)wid * N_NODES) / nW);
  const int n1 = (int)(((long long)(wid + 1) * N_NODES) / nW);

  if (n0 < n1) {
    int nu = RFL(n0);
    const int p_end = RFL(rs[n1]);
    int nend = RFL(rs[nu + 1]);
    int f1 = (nu + 1 < N_NODES) ? (nu + 1) : (N_NODES - 1);
    int f2 = (nu + 2 <= N_NODES) ? (nu + 2) : N_NODES;
    int nendN = RFL(rs[f2]);
    float ern  = er[nu * 4 + head];
    float ernN = er[f1 * 4 + head];
    u16x8 rv_cur = *(const u16x8*)(resbuf + (size_t)nu * 256 + li8);
    u16x8 rvN    = *(const u16x8*)(resbuf + (size_t)f1 * 256 + li8);

    float4 accA = make_float4(0.f, 0.f, 0.f, 0.f);
    float4 accB = make_float4(0.f, 0.f, 0.f, 0.f);
    float ssum = 0.f;

    int2 snA, snB, snC, snD, snE, snF, snG, snH;
    float evA, evB, evC, evD, evE, evF, evG, evH;
    u16x8 hvA, hvB, hvC, hvD, hvE, hvF, hvG, hvH;

    int p = RFL(rs[nu]);             // multiple of 4 (slots are relative)
    PRO(A, p);      PRO(B, p + 2);  PRO(C, p + 4);  PRO(D, p + 6);
    PRO(E, p + 8);  PRO(F, p + 10);
    if (p + 12 < p_end) snG = *(const int2*)(esrc + p + 12);
    if (p + 14 < p_end) snH = *(const int2*)(esrc + p + 14);
    __builtin_amdgcn_sched_barrier(0);

    while (p < p_end) {
      STEP(A, G); p += 2; if (p >= p_end) break;
      STEP(B, H); p += 2; if (p >= p_end) break;
      STEP(C, A); p += 2; if (p >= p_end) break;
      STEP(D, B); p += 2; if (p >= p_end) break;
      STEP(E, C); p += 2; if (p >= p_end) break;
      STEP(F, D); p += 2; if (p >= p_end) break;
      STEP(G, E); p += 2; if (p >= p_end) break;
      STEP(H, F); p += 2;
    }

    // drain: finalize last node + trailing zero-degree nodes
    while (nu < n1) {
      FIN(nu);
      accA.x=0.f; accA.y=0.f; accA.z=0.f; accA.w=0.f;
      accB.x=0.f; accB.y=0.f; accB.z=0.f; accB.w=0.f; ssum = 0.f;
      nu++;
      if (nu < n1) rv_cur = *(const u16x8*)(resbuf + (size_t)nu * 256 + li8);
    }
  }

  __syncthreads();
  const int t = threadIdx.x;
  if (t < 64)       atomicAdd(&bn[t * 16], ls[t]);          // line-padded slots
  else if (t < 128) atomicAdd(&bn[t * 16], lq[t - 64]);
}

// ---------------- batchnorm apply (reads line-padded stats) ----------------
__global__ __launch_bounds__(256) void k_bn_apply(float* __restrict__ out,
                                                  const float* __restrict__ bn,
                                                  const float* __restrict__ gamma,
                                                  const float* __restrict__ beta)
{
  __shared__ float sc[64], sh[64];
  const int t = threadIdx.x;
  if (t < 64) {
    float mean = bn[t * 16] * (1.0f / N_NODES);
    float var = bn[(t + 64) * 16] * (1.0f / N_NODES) - mean * mean;
    float s = gamma[t] * rsqrtf(var + BN_EPS);
    sc[t] = s;
    sh[t] = beta[t] - mean * s;
  }
  __syncthreads();
  const int i = blockIdx.x * 256 + t;
  if (i >= N_NODES * 16) return;
  const int d0 = (i & 15) * 4;
  float4 v = *(float4*)(out + (size_t)i * 4);
  v.x = fmaf(v.x, sc[d0 + 0], sh[d0 + 0]);
  v.y = fmaf(v.y, sc[d0 + 1], sh[d0 + 1]);
  v.z = fmaf(v.z, sc[d0 + 2], sh[d0 + 2]);
  v.w = fmaf(v.w, sc[d0 + 3], sh[d0 + 3]);
  *(float4*)(out + (size_t)i * 4) = v;
}

extern "C" void kernel_launch(void* const* d_in, const int* in_sizes, int n_in,
                              void* d_out, int out_size, void* d_ws, size_t ws_size,
                              hipStream_t stream)
{
  const float* feats  = (const float*)d_in[0];
  const int*   src    = (const int*)d_in[1];
  const int*   dst    = (const int*)d_in[2];
  const float* fc_w   = (const float*)d_in[3];
  const float* attn_l = (const float*)d_in[4];
  const float* attn_r = (const float*)d_in[5];
  const float* res_w  = (const float*)d_in[6];
  const float* bias   = (const float*)d_in[7];
  const float* gamma  = (const float*)d_in[8];
  const float* beta   = (const float*)d_in[9];

  char* ws = (char*)d_ws;
  unsigned short* Ab     = (unsigned short*)(ws + OFF_AB);
  unsigned short* Bb     = (unsigned short*)(ws + OFF_BB);
  unsigned short* hbuf   = (unsigned short*)(ws + OFF_H);
  unsigned short* resbuf = (unsigned short*)(ws + OFF_RES);
  float* elb    = (float*)(ws + OFF_EL);
  float* erb    = (float*)(ws + OFF_ER);
  int*   deg    = (int*)(ws + OFF_DEG);
  int*   rsb    = (int*)(ws + OFF_RS);
  float* bnb    = (float*)(ws + OFF_BNP);
  int*   esrc   = (int*)(ws + OFF_ESRC);
  int*   bsums  = (int*)(ws + OFF_BS);
  float* outp   = (float*)d_out;
  int*   rankp  = (int*)d_out;          // scratch: first 6.4 MB of out

  hipMemsetAsync(deg, 0, N_NODES * sizeof(int), stream);
  hipMemsetAsync(bnb, 0, 128 * 16 * sizeof(float), stream);

  k_pre<<<12539, 256, 0, stream>>>(feats, fc_w, res_w, dst, Ab, Bb, deg, hbuf, elb, rankp);
  k_scan1<<<98, 256, 0, stream>>>(deg, rsb, bsums);
  k_scan3<<<391, 256, 0, stream>>>(rsb, bsums, deg, esrc);
  k_place<<<6250, 256, 0, stream>>>(src, dst, rsb, rankp, esrc);
  k_mm<<<dim3(782, 2), 256, 0, stream>>>(Ab, Bb, bias, attn_l, attn_r,
                                         hbuf, resbuf, elb, erb);
  k_agg<<<2048, 256, 0, stream>>>(hbuf, resbuf, elb, erb, rsb, esrc, outp, bnb);
  k_bn_apply<<<6250, 256, 0, stream>>>(outp, bnb, gamma, beta);
}